// Round 1
// baseline (519.860 us; speedup 1.0000x reference)
//
#include <hip/hip_runtime.h>
#include <hip/hip_bf16.h>

#define NN 20000
#define NE 320000
#define NG 16
#define PSPLIT 32
#define NSCANB 79  // ceil(20000/256)

// ---------------- CSR build ----------------

__global__ void hist_kernel(const int* __restrict__ dst, int* __restrict__ indeg, int E) {
  int e = blockIdx.x * 256 + threadIdx.x;
  if (e < E) atomicAdd(&indeg[dst[e]], 1);
}

// hierarchical exclusive scan: per-block scan + block sums
__global__ void scan1_kernel(const int* __restrict__ in, int* __restrict__ outp,
                             int* __restrict__ bsum, int n) {
  int b = blockIdx.x, t = threadIdx.x;
  int i = b * 256 + t;
  int lane = t & 63, wv = t >> 6;
  __shared__ int ws[4];
  int v = (i < n) ? in[i] : 0;
  int x = v;
#pragma unroll
  for (int off = 1; off < 64; off <<= 1) {
    int y = __shfl_up(x, off);
    if (lane >= off) x += y;
  }
  if (lane == 63) ws[wv] = x;
  __syncthreads();
  int add = 0;
  for (int w2 = 0; w2 < wv; w2++) add += ws[w2];
  x += add;
  if (i < n) outp[i] = x - v;  // block-local exclusive
  if (t == 255) bsum[b] = x;   // block total
}

// scan block sums (nb <= 128), write offsets + grand total to rowptr[NN]
__global__ void scan2_kernel(const int* __restrict__ bsum, int* __restrict__ boff,
                             int* __restrict__ rp_end, int nb) {
  int t = threadIdx.x;  // 128
  int lane = t & 63, wv = t >> 6;
  __shared__ int ws[2];
  int v = (t < nb) ? bsum[t] : 0;
  int x = v;
#pragma unroll
  for (int off = 1; off < 64; off <<= 1) {
    int y = __shfl_up(x, off);
    if (lane >= off) x += y;
  }
  if (lane == 63) ws[wv] = x;
  __syncthreads();
  if (wv == 1) x += ws[0];
  if (t < nb) boff[t] = x - v;
  if (t == 127) *rp_end = x;
}

__global__ void scan3_kernel(int* __restrict__ outp, const int* __restrict__ boff, int n) {
  int i = blockIdx.x * 256 + threadIdx.x;
  if (i < n) outp[i] += boff[blockIdx.x];
}

__global__ void scatter_kernel(const int* __restrict__ src, const int* __restrict__ dst,
                               const int* __restrict__ rowptr, int* __restrict__ cursor,
                               int* __restrict__ csr_src, int E) {
  int e = blockIdx.x * 256 + threadIdx.x;
  if (e < E) {
    int d = dst[e];
    int p = atomicAdd(&cursor[d], 1);
    csr_src[rowptr[d] + p] = src[e];
  }
}

// ---------------- layer-1 attention vectors pushed through W1 ----------------

__global__ void prep_wlr_kernel(const float* __restrict__ W1, const float* __restrict__ al1,
                                const float* __restrict__ ar1, float* __restrict__ wlr) {
  int t = blockIdx.x * 256 + threadIdx.x;  // 768 total
  if (t >= 768) return;
  int k = t & 127;
  int j = t >> 7;  // 0..5
  int h = j % 3;
  const float* av = (j < 3 ? al1 : ar1) + h * 128;
  const float* wrow = W1 + (size_t)k * 384 + h * 128;
  float s = 0.f;
#pragma unroll 4
  for (int d = 0; d < 128; d++) s += wrow[d] * av[d];
  wlr[j * 128 + k] = s;
}

// el1/er1 for all nodes: one wave per node
__global__ void elr_kernel(const float* __restrict__ x, const float* __restrict__ wlr,
                           float* __restrict__ el, float* __restrict__ er, int N) {
  __shared__ float wl_s[768];
  int t = threadIdx.x;
  for (int i = t; i < 768; i += 256) wl_s[i] = wlr[i];
  __syncthreads();
  int w = (blockIdx.x * 256 + t) >> 6;
  int lane = t & 63;
  if (w >= N) return;
  float v0 = x[(size_t)w * 128 + lane], v1 = x[(size_t)w * 128 + 64 + lane];
  float s[6];
#pragma unroll
  for (int j = 0; j < 6; j++) s[j] = v0 * wl_s[j * 128 + lane] + v1 * wl_s[j * 128 + 64 + lane];
#pragma unroll
  for (int off = 32; off; off >>= 1)
#pragma unroll
    for (int j = 0; j < 6; j++) s[j] += __shfl_down(s[j], off);
  if (lane == 0) {
    el[w * 3 + 0] = s[0]; el[w * 3 + 1] = s[1]; el[w * 3 + 2] = s[2];
    er[w * 3 + 0] = s[3]; er[w * 3 + 1] = s[4]; er[w * 3 + 2] = s[5];
  }
}

// ---------------- layer-1 aggregation in x-space ----------------

__global__ void aggregate_x_kernel(const float* __restrict__ x, const float* __restrict__ el,
                                   const float* __restrict__ er, const int* __restrict__ rowptr,
                                   const int* __restrict__ csr_src, float* __restrict__ aggx) {
  int n = blockIdx.x;
  int t = threadIdx.x;  // 128
  __shared__ float wbuf[3][128];
  __shared__ int sbuf[128];
  __shared__ float red[6];
  __shared__ float4 accbuf[3][4][32];
  int rs = rowptr[n];
  int deg = rowptr[n + 1] - rs;
  float er0 = er[n * 3 + 0], er1 = er[n * 3 + 1], er2 = er[n * 3 + 2];
  float p0 = 0.f, p1 = 0.f, p2 = 0.f;
  int g = t >> 5, dq = t & 31;
  const float* xd = x + dq * 4;
  float4 a0 = make_float4(0, 0, 0, 0), a1 = a0, a2 = a0;
  for (int base = 0; base < deg; base += 128) {
    int cnt = min(128, deg - base);
    if (t < cnt) {
      int s = csr_src[rs + base + t];
      sbuf[t] = s;
      float e0 = el[s * 3 + 0] + er0, e1 = el[s * 3 + 1] + er1, e2 = el[s * 3 + 2] + er2;
      e0 = e0 > 0.f ? e0 : 0.2f * e0;
      e1 = e1 > 0.f ? e1 : 0.2f * e1;
      e2 = e2 > 0.f ? e2 : 0.2f * e2;
      float w0 = __expf(e0), w1 = __expf(e1), w2 = __expf(e2);
      wbuf[0][t] = w0; wbuf[1][t] = w1; wbuf[2][t] = w2;
      p0 += w0; p1 += w1; p2 += w2;
    }
    __syncthreads();
    int j = g;
    for (; j + 4 < cnt; j += 8) {
      int s0 = sbuf[j], s1 = sbuf[j + 4];
      float4 v0 = *(const float4*)(xd + (size_t)s0 * 128);
      float4 v1 = *(const float4*)(xd + (size_t)s1 * 128);
      float w00 = wbuf[0][j], w01 = wbuf[1][j], w02 = wbuf[2][j];
      float w10 = wbuf[0][j + 4], w11 = wbuf[1][j + 4], w12 = wbuf[2][j + 4];
      a0.x += w00 * v0.x + w10 * v1.x; a0.y += w00 * v0.y + w10 * v1.y;
      a0.z += w00 * v0.z + w10 * v1.z; a0.w += w00 * v0.w + w10 * v1.w;
      a1.x += w01 * v0.x + w11 * v1.x; a1.y += w01 * v0.y + w11 * v1.y;
      a1.z += w01 * v0.z + w11 * v1.z; a1.w += w01 * v0.w + w11 * v1.w;
      a2.x += w02 * v0.x + w12 * v1.x; a2.y += w02 * v0.y + w12 * v1.y;
      a2.z += w02 * v0.z + w12 * v1.z; a2.w += w02 * v0.w + w12 * v1.w;
    }
    for (; j < cnt; j += 4) {
      int s = sbuf[j];
      float4 v = *(const float4*)(xd + (size_t)s * 128);
      float w0 = wbuf[0][j], w1 = wbuf[1][j], w2 = wbuf[2][j];
      a0.x += w0 * v.x; a0.y += w0 * v.y; a0.z += w0 * v.z; a0.w += w0 * v.w;
      a1.x += w1 * v.x; a1.y += w1 * v.y; a1.z += w1 * v.z; a1.w += w1 * v.w;
      a2.x += w2 * v.x; a2.y += w2 * v.y; a2.z += w2 * v.z; a2.w += w2 * v.w;
    }
    __syncthreads();
  }
  for (int off = 32; off; off >>= 1) {
    p0 += __shfl_down(p0, off);
    p1 += __shfl_down(p1, off);
    p2 += __shfl_down(p2, off);
  }
  int wv = t >> 6, ln = t & 63;
  if (ln == 0) { red[wv * 3 + 0] = p0; red[wv * 3 + 1] = p1; red[wv * 3 + 2] = p2; }
  accbuf[0][g][dq] = a0;
  accbuf[1][g][dq] = a1;
  accbuf[2][g][dq] = a2;
  __syncthreads();
  if (t < 96) {
    int h = t >> 5, d = t & 31;
    float4 s0 = accbuf[h][0][d], s1 = accbuf[h][1][d], s2 = accbuf[h][2][d], s3 = accbuf[h][3][d];
    float dn = red[h] + red[3 + h];
    float inv = dn > 0.f ? 1.f / dn : 0.f;
    float4 r;
    r.x = (s0.x + s1.x + s2.x + s3.x) * inv;
    r.y = (s0.y + s1.y + s2.y + s3.y) * inv;
    r.z = (s0.z + s1.z + s2.z + s3.z) * inv;
    r.w = (s0.w + s1.w + s2.w + s3.w) * inv;
    *(float4*)&aggx[(size_t)n * 384 + h * 128 + d * 4] = r;
  }
}

// ---------------- row-per-lane GEMM ----------------
// Block = 256 threads = 4 waves; block tile = 64 rows x 64 cols; wave = 64 rows x 16 cols;
// lane owns one output row. A staged in LDS as [q=k/4][m] float4 planes -> one contiguous
// ds_read_b128 per lane covers 4 k's (lane-linear 1024B, conflict-free). B (weights,
// L1/L2-resident) read with wave-uniform dwordx4 loads straight to registers: zero LDS
// traffic for B, so the LDS read port (the 33%-VALU ceiling of the old 4x4-microtile
// design) is off the critical path. 16 independent FMA chains/lane give ILP.
// NCB = column-blocks (N/64). HEADS: A advances 128 cols per 128-col output group.

#define NROWT 313  // ceil(20000/64)

template <int K, int NCB, bool HEADS, bool BIAS_ELU>
__launch_bounds__(256, 4)
__global__ void gemm_rowlane_kernel(const float* __restrict__ A, int lda,
                                    const float* __restrict__ B, int ldb,
                                    float* __restrict__ C, int ldc,
                                    const float* __restrict__ bias) {
  __shared__ float4 As[8 * 64];  // [q][m]
  int t = threadIdx.x;
  int lane = t & 63;
  int w = t >> 6;

  // bijective XCD-chunk swizzle (m204): consecutive logical tiles -> same XCD L2,
  // so the NCB col-blocks sharing one A row-panel hit in L2.
  constexpr int NWG = NROWT * NCB;
  constexpr int QW = NWG >> 3, RW = NWG & 7;
  int o = blockIdx.x;
  int xcd = o & 7, i8 = o >> 3;
  int wgid = (xcd < RW ? xcd * (QW + 1) : RW * (QW + 1) + (xcd - RW) * QW) + i8;
  int rt = wgid / NCB;
  int cb = wgid - rt * NCB;
  int m0 = rt * 64;
  int col0 = cb * 64 + w * 16;
  const float* Ab = A + (HEADS ? (size_t)(cb >> 1) * 128 : 0);
  int row = m0 + lane;

  float acc[16];
#pragma unroll
  for (int c = 0; c < 16; ++c) acc[c] = 0.f;

  for (int k0 = 0; k0 < K; k0 += 32) {
    // stage A tile 64 rows x 32 k (coalesced reads, scattered-plane writes)
#pragma unroll
    for (int p = 0; p < 2; ++p) {
      int i = p * 256 + t;
      int r = i >> 3, q = i & 7;
      int rowr = m0 + r;
      if (rowr > NN - 1) rowr = NN - 1;  // tail tile: duplicate last row (stores guarded)
      As[q * 64 + r] = *(const float4*)&Ab[(size_t)rowr * lda + k0 + q * 4];
    }
    __syncthreads();
#pragma unroll
    for (int q = 0; q < 8; ++q) {
      float4 a4 = As[q * 64 + lane];  // contiguous b128: 4 k's of this lane's row
      float af[4] = {a4.x, a4.y, a4.z, a4.w};
#pragma unroll
      for (int j = 0; j < 4; ++j) {
        const float* Brow = B + (size_t)(k0 + q * 4 + j) * ldb + col0;
        float4 b0 = *(const float4*)(Brow + 0);
        float4 b1 = *(const float4*)(Brow + 4);
        float4 b2 = *(const float4*)(Brow + 8);
        float4 b3 = *(const float4*)(Brow + 12);
        float aj = af[j];
        acc[0] += aj * b0.x;  acc[1] += aj * b0.y;  acc[2] += aj * b0.z;  acc[3] += aj * b0.w;
        acc[4] += aj * b1.x;  acc[5] += aj * b1.y;  acc[6] += aj * b1.z;  acc[7] += aj * b1.w;
        acc[8] += aj * b2.x;  acc[9] += aj * b2.y;  acc[10] += aj * b2.z; acc[11] += aj * b2.w;
        acc[12] += aj * b3.x; acc[13] += aj * b3.y; acc[14] += aj * b3.z; acc[15] += aj * b3.w;
      }
    }
    __syncthreads();
  }

  if (row < NN) {
    float* Cr = C + (size_t)row * ldc + col0;
#pragma unroll
    for (int cc = 0; cc < 4; ++cc) {
      float4 v = make_float4(acc[cc * 4 + 0], acc[cc * 4 + 1], acc[cc * 4 + 2], acc[cc * 4 + 3]);
      if (BIAS_ELU) {
        const float* bp = bias + col0 + cc * 4;
        v.x += bp[0]; v.y += bp[1]; v.z += bp[2]; v.w += bp[3];
        v.x = v.x > 0.f ? v.x : expm1f(v.x);
        v.y = v.y > 0.f ? v.y : expm1f(v.y);
        v.z = v.z > 0.f ? v.z : expm1f(v.z);
        v.w = v.w > 0.f ? v.w : expm1f(v.w);
      }
      *(float4*)(Cr + cc * 4) = v;
    }
  }
}

// ---------------- attention coefficients (layer 2, H=1, reads f2) ----------------

__global__ void att_coef_kernel(const float* __restrict__ f, const float* __restrict__ al,
                                const float* __restrict__ ar, float* __restrict__ el,
                                float* __restrict__ er, int NH) {
  int w = (blockIdx.x * 256 + threadIdx.x) >> 6;
  int lane = threadIdx.x & 63;
  if (w >= NH) return;
  const float* fr = f + (size_t)w * 128;
  float v0 = fr[lane], v1 = fr[64 + lane];
  float a0 = al[lane], a1 = al[64 + lane];
  float r0 = ar[lane], r1 = ar[64 + lane];
  float se = v0 * a0 + v1 * a1;
  float sr = v0 * r0 + v1 * r1;
  for (int off = 32; off; off >>= 1) {
    se += __shfl_down(se, off);
    sr += __shfl_down(sr, off);
  }
  if (lane == 0) { el[w] = se; er[w] = sr; }
}

// ---------------- layer-2 aggregation (H=1, gathers f2) ----------------

__global__ void aggregate1_kernel(const float* __restrict__ f, const float* __restrict__ el,
                                  const float* __restrict__ er, const float* __restrict__ bias,
                                  const int* __restrict__ rowptr, const int* __restrict__ csr_src,
                                  float* __restrict__ out) {
  int n = blockIdx.x;
  int t = threadIdx.x;
  __shared__ float wbuf[128];
  __shared__ int sbuf[128];
  __shared__ float red[2];
  __shared__ float4 accbuf[4][32];
  int rs = rowptr[n];
  int deg = rowptr[n + 1] - rs;
  float ern = er[n];
  float psum = 0.f;
  int g = t >> 5;
  int d = (t & 31) * 4;
  const float* fd = f + d;
  float4 acc = make_float4(0.f, 0.f, 0.f, 0.f);
  for (int base = 0; base < deg; base += 128) {
    int cnt = min(128, deg - base);
    if (t < cnt) {
      int s = csr_src[rs + base + t];
      sbuf[t] = s;
      float e = el[s] + ern;
      e = e > 0.f ? e : 0.2f * e;
      float w = __expf(e);
      wbuf[t] = w;
      psum += w;
    }
    __syncthreads();
    int j = g;
    for (; j + 4 < cnt; j += 8) {
      int s0 = sbuf[j], s1 = sbuf[j + 4];
      float4 v0 = *(const float4*)(fd + (size_t)s0 * 128);
      float4 v1 = *(const float4*)(fd + (size_t)s1 * 128);
      float w0 = wbuf[j], w1 = wbuf[j + 4];
      acc.x += w0 * v0.x + w1 * v1.x;
      acc.y += w0 * v0.y + w1 * v1.y;
      acc.z += w0 * v0.z + w1 * v1.z;
      acc.w += w0 * v0.w + w1 * v1.w;
    }
    for (; j < cnt; j += 4) {
      int s = sbuf[j];
      float4 v = *(const float4*)(fd + (size_t)s * 128);
      float w = wbuf[j];
      acc.x += w * v.x; acc.y += w * v.y; acc.z += w * v.z; acc.w += w * v.w;
    }
    __syncthreads();
  }
  for (int off = 32; off; off >>= 1) psum += __shfl_down(psum, off);
  int wv = t >> 6, ln = t & 63;
  if (ln == 0) red[wv] = psum;
  accbuf[g][t & 31] = acc;
  __syncthreads();
  if (t < 32) {
    float4 a0 = accbuf[0][t], a1 = accbuf[1][t], a2 = accbuf[2][t], a3 = accbuf[3][t];
    float dn = red[0] + red[1];
    float inv = dn > 0.f ? 1.f / dn : 0.f;
    const float* bp = bias + t * 4;
    float4 r;
    r.x = (a0.x + a1.x + a2.x + a3.x) * inv + bp[0];
    r.y = (a0.y + a1.y + a2.y + a3.y) * inv + bp[1];
    r.z = (a0.z + a1.z + a2.z + a3.z) * inv + bp[2];
    r.w = (a0.w + a1.w + a2.w + a3.w) * inv + bp[3];
    *(float4*)&out[(size_t)n * 128 + t * 4] = r;
  }
}

// ---------------- mean-pool: 2-stage ----------------

__global__ void pool_partial_kernel(const float* __restrict__ h2, const int* __restrict__ gid,
                                    float* __restrict__ sums, int N) {
  int g = blockIdx.x / PSPLIT;
  int sp = blockIdx.x % PSPLIT;
  int tid = threadIdx.x;
  int lo0 = 0, hi0 = N;
  while (lo0 < hi0) { int m = (lo0 + hi0) >> 1; if (gid[m] < g) lo0 = m + 1; else hi0 = m; }
  int lo1 = lo0, hi1 = N;
  while (lo1 < hi1) { int m = (lo1 + hi1) >> 1; if (gid[m] < g + 1) lo1 = m + 1; else hi1 = m; }
  float a0 = 0.f, a1 = 0.f, a2 = 0.f, a3 = 0.f;
  int n = lo0 + sp;
  for (; n + 3 * PSPLIT < lo1; n += 4 * PSPLIT) {
    a0 += h2[(size_t)n * 128 + tid];
    a1 += h2[(size_t)(n + PSPLIT) * 128 + tid];
    a2 += h2[(size_t)(n + 2 * PSPLIT) * 128 + tid];
    a3 += h2[(size_t)(n + 3 * PSPLIT) * 128 + tid];
  }
  for (; n < lo1; n += PSPLIT) a0 += h2[(size_t)n * 128 + tid];
  float acc = (a0 + a1) + (a2 + a3);
  atomicAdd(&sums[g * 128 + tid], acc);
}

__global__ void pool_final_kernel(const float* __restrict__ sums, const int* __restrict__ gid,
                                  const float* __restrict__ linW, const float* __restrict__ linb,
                                  float* __restrict__ out, int N) {
  int g = blockIdx.x;
  int tid = threadIdx.x;
  int lo0 = 0, hi0 = N;
  while (lo0 < hi0) { int m = (lo0 + hi0) >> 1; if (gid[m] < g) lo0 = m + 1; else hi0 = m; }
  int lo1 = lo0, hi1 = N;
  while (lo1 < hi1) { int m = (lo1 + hi1) >> 1; if (gid[m] < g + 1) lo1 = m + 1; else hi1 = m; }
  int cnt = lo1 - lo0;
  float hg = sums[g * 128 + tid] / (float)(cnt > 0 ? cnt : 1);
  __shared__ float hgs[128];
  hgs[tid] = hg;
  __syncthreads();
  float o = linb[tid];
#pragma unroll 4
  for (int dd = 0; dd < 128; dd++) o += hgs[dd] * linW[dd * 128 + tid];
  out[g * 128 + tid] = fmaxf(o, 0.f);
}

// ---------------- launch ----------------

extern "C" void kernel_launch(void* const* d_in, const int* in_sizes, int n_in,
                              void* d_out, int out_size, void* d_ws, size_t ws_size,
                              hipStream_t stream) {
  const float* x    = (const float*)d_in[0];
  const int*   src  = (const int*)d_in[1];
  const int*   dst  = (const int*)d_in[2];
  const int*   gid  = (const int*)d_in[3];
  const float* W1   = (const float*)d_in[4];
  const float* al1  = (const float*)d_in[5];
  const float* ar1  = (const float*)d_in[6];
  const float* b1   = (const float*)d_in[7];
  const float* W2   = (const float*)d_in[8];
  const float* al2  = (const float*)d_in[9];
  const float* ar2  = (const float*)d_in[10];
  const float* b2   = (const float*)d_in[11];
  const float* linW = (const float*)d_in[12];
  const float* linb = (const float*)d_in[13];
  float* out = (float*)d_out;

  char* ws = (char*)d_ws;
  size_t off = 0;
  auto alloc = [&](size_t bytes) -> void* {
    void* p = ws + off;
    off += (bytes + 255) & ~(size_t)255;
    return p;
  };
  float* aggx    = (float*)alloc((size_t)NN * 384 * 4);
  float* h1      = (float*)alloc((size_t)NN * 384 * 4);
  float* f2      = (float*)alloc((size_t)NN * 128 * 4);
  float* h2      = (float*)alloc((size_t)NN * 128 * 4);
  float* el1     = (float*)alloc((size_t)NN * 3 * 4);
  float* er1     = (float*)alloc((size_t)NN * 3 * 4);
  float* el2     = (float*)alloc((size_t)NN * 4);
  float* er2     = (float*)alloc((size_t)NN * 4);
  float* wlr     = (float*)alloc((size_t)768 * 4);
  int*   rowptr  = (int*)alloc((size_t)(NN + 1) * 4);
  int*   csr_src = (int*)alloc((size_t)NE * 4);
  int*   bsum    = (int*)alloc((size_t)NSCANB * 4);
  int*   boff    = (int*)alloc((size_t)NSCANB * 4);
  // zero-initialized region (single memset): indeg, cursor, gsums
  int*   indeg   = (int*)alloc((size_t)NN * 4);
  int*   cursor  = (int*)alloc((size_t)NN * 4);
  float* gsums   = (float*)alloc((size_t)NG * 128 * 4);
  (void)ws_size;
  size_t zbytes = (char*)(gsums + NG * 128) - (char*)indeg;
  hipMemsetAsync(indeg, 0, zbytes, stream);

  // CSR build (hierarchical scan)
  hist_kernel<<<(NE + 255) / 256, 256, 0, stream>>>(dst, indeg, NE);
  scan1_kernel<<<NSCANB, 256, 0, stream>>>(indeg, rowptr, bsum, NN);
  scan2_kernel<<<1, 128, 0, stream>>>(bsum, boff, rowptr + NN, NSCANB);
  scan3_kernel<<<NSCANB, 256, 0, stream>>>(rowptr, boff, NN);
  scatter_kernel<<<(NE + 255) / 256, 256, 0, stream>>>(src, dst, rowptr, cursor, csr_src, NE);

  // Layer 1 (x-space): wlr -> el/er -> aggregate x -> per-head GEMM with bias+ELU
  prep_wlr_kernel<<<3, 256, 0, stream>>>(W1, al1, ar1, wlr);
  elr_kernel<<<(NN + 3) / 4, 256, 0, stream>>>(x, wlr, el1, er1, NN);
  aggregate_x_kernel<<<NN, 128, 0, stream>>>(x, el1, er1, rowptr, csr_src, aggx);
  gemm_rowlane_kernel<128, 6, true, true><<<NROWT * 6, 256, 0, stream>>>(
      aggx, 384, W1, 384, h1, 384, b1);

  // Layer 2: f2 = h1 @ W2 ; el2/er2 ; aggregate(+b2) -> h2
  gemm_rowlane_kernel<384, 2, false, false><<<NROWT * 2, 256, 0, stream>>>(
      h1, 384, W2, 128, f2, 128, nullptr);
  att_coef_kernel<<<(NN + 3) / 4, 256, 0, stream>>>(f2, al2, ar2, el2, er2, NN);
  aggregate1_kernel<<<NN, 128, 0, stream>>>(f2, el2, er2, b2, rowptr, csr_src, h2);

  // Mean-pool + linear head
  pool_partial_kernel<<<NG * PSPLIT, 128, 0, stream>>>(h2, gid, gsums, NN);
  pool_final_kernel<<<NG, 128, 0, stream>>>(gsums, gid, linW, linb, out, NN);
}

// Round 2
// 334.795 us; speedup vs baseline: 1.5528x; 1.5528x over previous
//
#include <hip/hip_runtime.h>
#include <hip/hip_bf16.h>

#define NN 20000
#define NE 320000
#define NG 16
#define PSPLIT 32
#define NSCANB 79  // ceil(20000/256)

// ---------------- CSR build ----------------

__global__ void hist_kernel(const int* __restrict__ dst, int* __restrict__ indeg, int E) {
  int e = blockIdx.x * 256 + threadIdx.x;
  if (e < E) atomicAdd(&indeg[dst[e]], 1);
}

// hierarchical exclusive scan: per-block scan + block sums
__global__ void scan1_kernel(const int* __restrict__ in, int* __restrict__ outp,
                             int* __restrict__ bsum, int n) {
  int b = blockIdx.x, t = threadIdx.x;
  int i = b * 256 + t;
  int lane = t & 63, wv = t >> 6;
  __shared__ int ws[4];
  int v = (i < n) ? in[i] : 0;
  int x = v;
#pragma unroll
  for (int off = 1; off < 64; off <<= 1) {
    int y = __shfl_up(x, off);
    if (lane >= off) x += y;
  }
  if (lane == 63) ws[wv] = x;
  __syncthreads();
  int add = 0;
  for (int w2 = 0; w2 < wv; w2++) add += ws[w2];
  x += add;
  if (i < n) outp[i] = x - v;  // block-local exclusive
  if (t == 255) bsum[b] = x;   // block total
}

// scan block sums (nb <= 128), write offsets + grand total to rowptr[NN]
__global__ void scan2_kernel(const int* __restrict__ bsum, int* __restrict__ boff,
                             int* __restrict__ rp_end, int nb) {
  int t = threadIdx.x;  // 128
  int lane = t & 63, wv = t >> 6;
  __shared__ int ws[2];
  int v = (t < nb) ? bsum[t] : 0;
  int x = v;
#pragma unroll
  for (int off = 1; off < 64; off <<= 1) {
    int y = __shfl_up(x, off);
    if (lane >= off) x += y;
  }
  if (lane == 63) ws[wv] = x;
  __syncthreads();
  if (wv == 1) x += ws[0];
  if (t < nb) boff[t] = x - v;
  if (t == 127) *rp_end = x;
}

__global__ void scan3_kernel(int* __restrict__ outp, const int* __restrict__ boff, int n) {
  int i = blockIdx.x * 256 + threadIdx.x;
  if (i < n) outp[i] += boff[blockIdx.x];
}

__global__ void scatter_kernel(const int* __restrict__ src, const int* __restrict__ dst,
                               const int* __restrict__ rowptr, int* __restrict__ cursor,
                               int* __restrict__ csr_src, int E) {
  int e = blockIdx.x * 256 + threadIdx.x;
  if (e < E) {
    int d = dst[e];
    int p = atomicAdd(&cursor[d], 1);
    csr_src[rowptr[d] + p] = src[e];
  }
}

// ---------------- layer-1 attention vectors pushed through W1 ----------------

__global__ void prep_wlr_kernel(const float* __restrict__ W1, const float* __restrict__ al1,
                                const float* __restrict__ ar1, float* __restrict__ wlr) {
  int t = blockIdx.x * 256 + threadIdx.x;  // 768 total
  if (t >= 768) return;
  int k = t & 127;
  int j = t >> 7;  // 0..5
  int h = j % 3;
  const float* av = (j < 3 ? al1 : ar1) + h * 128;
  const float* wrow = W1 + (size_t)k * 384 + h * 128;
  float s = 0.f;
#pragma unroll 4
  for (int d = 0; d < 128; d++) s += wrow[d] * av[d];
  wlr[j * 128 + k] = s;
}

// el1/er1 for all nodes: one wave per node
__global__ void elr_kernel(const float* __restrict__ x, const float* __restrict__ wlr,
                           float* __restrict__ el, float* __restrict__ er, int N) {
  __shared__ float wl_s[768];
  int t = threadIdx.x;
  for (int i = t; i < 768; i += 256) wl_s[i] = wlr[i];
  __syncthreads();
  int w = (blockIdx.x * 256 + t) >> 6;
  int lane = t & 63;
  if (w >= N) return;
  float v0 = x[(size_t)w * 128 + lane], v1 = x[(size_t)w * 128 + 64 + lane];
  float s[6];
#pragma unroll
  for (int j = 0; j < 6; j++) s[j] = v0 * wl_s[j * 128 + lane] + v1 * wl_s[j * 128 + 64 + lane];
#pragma unroll
  for (int off = 32; off; off >>= 1)
#pragma unroll
    for (int j = 0; j < 6; j++) s[j] += __shfl_down(s[j], off);
  if (lane == 0) {
    el[w * 3 + 0] = s[0]; el[w * 3 + 1] = s[1]; el[w * 3 + 2] = s[2];
    er[w * 3 + 0] = s[3]; er[w * 3 + 1] = s[4]; er[w * 3 + 2] = s[5];
  }
}

// ---------------- layer-1 aggregation in x-space ----------------

__global__ void aggregate_x_kernel(const float* __restrict__ x, const float* __restrict__ el,
                                   const float* __restrict__ er, const int* __restrict__ rowptr,
                                   const int* __restrict__ csr_src, float* __restrict__ aggx) {
  int n = blockIdx.x;
  int t = threadIdx.x;  // 128
  __shared__ float wbuf[3][128];
  __shared__ int sbuf[128];
  __shared__ float red[6];
  __shared__ float4 accbuf[3][4][32];
  int rs = rowptr[n];
  int deg = rowptr[n + 1] - rs;
  float er0 = er[n * 3 + 0], er1 = er[n * 3 + 1], er2 = er[n * 3 + 2];
  float p0 = 0.f, p1 = 0.f, p2 = 0.f;
  int g = t >> 5, dq = t & 31;
  const float* xd = x + dq * 4;
  float4 a0 = make_float4(0, 0, 0, 0), a1 = a0, a2 = a0;
  for (int base = 0; base < deg; base += 128) {
    int cnt = min(128, deg - base);
    if (t < cnt) {
      int s = csr_src[rs + base + t];
      sbuf[t] = s;
      float e0 = el[s * 3 + 0] + er0, e1 = el[s * 3 + 1] + er1, e2 = el[s * 3 + 2] + er2;
      e0 = e0 > 0.f ? e0 : 0.2f * e0;
      e1 = e1 > 0.f ? e1 : 0.2f * e1;
      e2 = e2 > 0.f ? e2 : 0.2f * e2;
      float w0 = __expf(e0), w1 = __expf(e1), w2 = __expf(e2);
      wbuf[0][t] = w0; wbuf[1][t] = w1; wbuf[2][t] = w2;
      p0 += w0; p1 += w1; p2 += w2;
    }
    __syncthreads();
    int j = g;
    for (; j + 4 < cnt; j += 8) {
      int s0 = sbuf[j], s1 = sbuf[j + 4];
      float4 v0 = *(const float4*)(xd + (size_t)s0 * 128);
      float4 v1 = *(const float4*)(xd + (size_t)s1 * 128);
      float w00 = wbuf[0][j], w01 = wbuf[1][j], w02 = wbuf[2][j];
      float w10 = wbuf[0][j + 4], w11 = wbuf[1][j + 4], w12 = wbuf[2][j + 4];
      a0.x += w00 * v0.x + w10 * v1.x; a0.y += w00 * v0.y + w10 * v1.y;
      a0.z += w00 * v0.z + w10 * v1.z; a0.w += w00 * v0.w + w10 * v1.w;
      a1.x += w01 * v0.x + w11 * v1.x; a1.y += w01 * v0.y + w11 * v1.y;
      a1.z += w01 * v0.z + w11 * v1.z; a1.w += w01 * v0.w + w11 * v1.w;
      a2.x += w02 * v0.x + w12 * v1.x; a2.y += w02 * v0.y + w12 * v1.y;
      a2.z += w02 * v0.z + w12 * v1.z; a2.w += w02 * v0.w + w12 * v1.w;
    }
    for (; j < cnt; j += 4) {
      int s = sbuf[j];
      float4 v = *(const float4*)(xd + (size_t)s * 128);
      float w0 = wbuf[0][j], w1 = wbuf[1][j], w2 = wbuf[2][j];
      a0.x += w0 * v.x; a0.y += w0 * v.y; a0.z += w0 * v.z; a0.w += w0 * v.w;
      a1.x += w1 * v.x; a1.y += w1 * v.y; a1.z += w1 * v.z; a1.w += w1 * v.w;
      a2.x += w2 * v.x; a2.y += w2 * v.y; a2.z += w2 * v.z; a2.w += w2 * v.w;
    }
    __syncthreads();
  }
  for (int off = 32; off; off >>= 1) {
    p0 += __shfl_down(p0, off);
    p1 += __shfl_down(p1, off);
    p2 += __shfl_down(p2, off);
  }
  int wv = t >> 6, ln = t & 63;
  if (ln == 0) { red[wv * 3 + 0] = p0; red[wv * 3 + 1] = p1; red[wv * 3 + 2] = p2; }
  accbuf[0][g][dq] = a0;
  accbuf[1][g][dq] = a1;
  accbuf[2][g][dq] = a2;
  __syncthreads();
  if (t < 96) {
    int h = t >> 5, d = t & 31;
    float4 s0 = accbuf[h][0][d], s1 = accbuf[h][1][d], s2 = accbuf[h][2][d], s3 = accbuf[h][3][d];
    float dn = red[h] + red[3 + h];
    float inv = dn > 0.f ? 1.f / dn : 0.f;
    float4 r;
    r.x = (s0.x + s1.x + s2.x + s3.x) * inv;
    r.y = (s0.y + s1.y + s2.y + s3.y) * inv;
    r.z = (s0.z + s1.z + s2.z + s3.z) * inv;
    r.w = (s0.w + s1.w + s2.w + s3.w) * inv;
    *(float4*)&aggx[(size_t)n * 384 + h * 128 + d * 4] = r;
  }
}

// ---------------- GEMM: 128 rows x 64 cols per block, 256 threads ----------------
// Wave w owns cols [cb*64 + w*16, +16) (wave-uniform -> B reads from LDS are
// same-address BROADCASTS: no bank traffic, no conflicts). Thread owns rows
// {lane, lane+64}: A-fragment is one contiguous ds_read_b128 = 4 k's.
// A staged as [q][r^q] float4 planes: the ^q XOR rotates the bank-quad so the
// 8 lanes that write the same row hit 8 distinct bank groups (the un-swizzled
// [q][r] layout was the 3.36M-cycle SQ_LDS_BANK_CONFLICT in the old kernel).
// LDS bytes/FMA drops 2.0 -> ~0.6 and B is broadcast, so the LDS read port
// (the old 30%-VALU ceiling) is off the critical path.
// B stays in LDS (NOT registers-from-global: round-1 showed the compiler does
// not pipeline uniform global loads -> 8% VALUBusy latency disaster).

#define NROWT2 157  // ceil(20000/128)

template <int K, int NCB, bool HEADS, bool BIAS_ELU>
__launch_bounds__(256, 3)
__global__ void gemm_bcast_kernel(const float* __restrict__ A, int lda,
                                  const float* __restrict__ B, int ldb,
                                  float* __restrict__ C, int ldc,
                                  const float* __restrict__ bias) {
  __shared__ float4 As[8 * 128];  // [q][r^q], 16 KB
  __shared__ float Bs[32 * 64];   // [kk][n], 8 KB
  int t = threadIdx.x;
  int lane = t & 63;
  int w = t >> 6;

  // bijective XCD-chunk swizzle: consecutive logical tiles -> same XCD L2,
  // so the NCB col-blocks sharing one A row-panel hit in L2.
  constexpr int NWG = NROWT2 * NCB;
  constexpr int QW = NWG >> 3, RW = NWG & 7;
  int o = blockIdx.x;
  int xcd = o & 7, i8 = o >> 3;
  int wgid = (xcd < RW ? xcd * (QW + 1) : RW * (QW + 1) + (xcd - RW) * QW) + i8;
  int rt = wgid / NCB;
  int cb = wgid - rt * NCB;
  int m0 = rt * 128;
  int col0 = cb * 64 + w * 16;
  const float* Ab = A + (HEADS ? (size_t)(cb >> 1) * 128 : 0);

  float acc[2][16];
#pragma unroll
  for (int rr = 0; rr < 2; ++rr)
#pragma unroll
    for (int c = 0; c < 16; ++c) acc[rr][c] = 0.f;

  for (int k0 = 0; k0 < K; k0 += 32) {
    // stage A: 128 rows x 32 k. Global: 8 lanes per row (coalesced 128B runs).
    // LDS: [q][r^q] -> conflict-free b128 writes and reads.
#pragma unroll
    for (int p = 0; p < 4; ++p) {
      int i = p * 256 + t;
      int r = i >> 3, q = i & 7;
      int rowr = m0 + r;
      if (rowr >= NN) rowr = NN - 1;  // tail tile: clamp (stores guarded)
      As[q * 128 + (r ^ q)] = *(const float4*)&Ab[(size_t)rowr * lda + k0 + q * 4];
    }
    // stage B: 32 k x 64 cols (16 lanes per k-row, coalesced 256B runs)
#pragma unroll
    for (int p = 0; p < 2; ++p) {
      int i = p * 256 + t;
      int kk = i >> 4, nq = (i & 15) * 4;
      *(float4*)&Bs[kk * 64 + nq] = *(const float4*)&B[(size_t)(k0 + kk) * ldb + cb * 64 + nq];
    }
    __syncthreads();
#pragma unroll
    for (int q = 0; q < 8; ++q) {
      float4 a0 = As[q * 128 + (lane ^ q)];
      float4 a1 = As[q * 128 + ((lane + 64) ^ q)];  // == (lane^q)+64
      float a0f[4] = {a0.x, a0.y, a0.z, a0.w};
      float a1f[4] = {a1.x, a1.y, a1.z, a1.w};
#pragma unroll
      for (int j = 0; j < 4; ++j) {
        const float* Brow = &Bs[(q * 4 + j) * 64 + w * 16];  // wave-uniform: broadcast
        float4 b0 = *(const float4*)(Brow + 0);
        float4 b1 = *(const float4*)(Brow + 4);
        float4 b2 = *(const float4*)(Brow + 8);
        float4 b3 = *(const float4*)(Brow + 12);
        float bf[16] = {b0.x, b0.y, b0.z, b0.w, b1.x, b1.y, b1.z, b1.w,
                        b2.x, b2.y, b2.z, b2.w, b3.x, b3.y, b3.z, b3.w};
        float aj0 = a0f[j], aj1 = a1f[j];
#pragma unroll
        for (int c = 0; c < 16; ++c) {
          acc[0][c] += aj0 * bf[c];
          acc[1][c] += aj1 * bf[c];
        }
      }
    }
    __syncthreads();
  }

  float bv[16];
  if (BIAS_ELU) {
#pragma unroll
    for (int c = 0; c < 16; ++c) bv[c] = bias[col0 + c];
  }
#pragma unroll
  for (int rr = 0; rr < 2; ++rr) {
    int row = m0 + lane + rr * 64;
    if (row < NN) {
      float* Cr = C + (size_t)row * ldc + col0;
#pragma unroll
      for (int cc = 0; cc < 4; ++cc) {
        float4 v = make_float4(acc[rr][cc * 4 + 0], acc[rr][cc * 4 + 1],
                               acc[rr][cc * 4 + 2], acc[rr][cc * 4 + 3]);
        if (BIAS_ELU) {
          v.x += bv[cc * 4 + 0]; v.y += bv[cc * 4 + 1];
          v.z += bv[cc * 4 + 2]; v.w += bv[cc * 4 + 3];
          v.x = v.x > 0.f ? v.x : expm1f(v.x);
          v.y = v.y > 0.f ? v.y : expm1f(v.y);
          v.z = v.z > 0.f ? v.z : expm1f(v.z);
          v.w = v.w > 0.f ? v.w : expm1f(v.w);
        }
        *(float4*)(Cr + cc * 4) = v;
      }
    }
  }
}

// ---------------- attention coefficients (layer 2, H=1, reads f2) ----------------

__global__ void att_coef_kernel(const float* __restrict__ f, const float* __restrict__ al,
                                const float* __restrict__ ar, float* __restrict__ el,
                                float* __restrict__ er, int NH) {
  int w = (blockIdx.x * 256 + threadIdx.x) >> 6;
  int lane = threadIdx.x & 63;
  if (w >= NH) return;
  const float* fr = f + (size_t)w * 128;
  float v0 = fr[lane], v1 = fr[64 + lane];
  float a0 = al[lane], a1 = al[64 + lane];
  float r0 = ar[lane], r1 = ar[64 + lane];
  float se = v0 * a0 + v1 * a1;
  float sr = v0 * r0 + v1 * r1;
  for (int off = 32; off; off >>= 1) {
    se += __shfl_down(se, off);
    sr += __shfl_down(sr, off);
  }
  if (lane == 0) { el[w] = se; er[w] = sr; }
}

// ---------------- layer-2 aggregation (H=1, gathers f2) ----------------

__global__ void aggregate1_kernel(const float* __restrict__ f, const float* __restrict__ el,
                                  const float* __restrict__ er, const float* __restrict__ bias,
                                  const int* __restrict__ rowptr, const int* __restrict__ csr_src,
                                  float* __restrict__ out) {
  int n = blockIdx.x;
  int t = threadIdx.x;
  __shared__ float wbuf[128];
  __shared__ int sbuf[128];
  __shared__ float red[2];
  __shared__ float4 accbuf[4][32];
  int rs = rowptr[n];
  int deg = rowptr[n + 1] - rs;
  float ern = er[n];
  float psum = 0.f;
  int g = t >> 5;
  int d = (t & 31) * 4;
  const float* fd = f + d;
  float4 acc = make_float4(0.f, 0.f, 0.f, 0.f);
  for (int base = 0; base < deg; base += 128) {
    int cnt = min(128, deg - base);
    if (t < cnt) {
      int s = csr_src[rs + base + t];
      sbuf[t] = s;
      float e = el[s] + ern;
      e = e > 0.f ? e : 0.2f * e;
      float w = __expf(e);
      wbuf[t] = w;
      psum += w;
    }
    __syncthreads();
    int j = g;
    for (; j + 4 < cnt; j += 8) {
      int s0 = sbuf[j], s1 = sbuf[j + 4];
      float4 v0 = *(const float4*)(fd + (size_t)s0 * 128);
      float4 v1 = *(const float4*)(fd + (size_t)s1 * 128);
      float w0 = wbuf[j], w1 = wbuf[j + 4];
      acc.x += w0 * v0.x + w1 * v1.x;
      acc.y += w0 * v0.y + w1 * v1.y;
      acc.z += w0 * v0.z + w1 * v1.z;
      acc.w += w0 * v0.w + w1 * v1.w;
    }
    for (; j < cnt; j += 4) {
      int s = sbuf[j];
      float4 v = *(const float4*)(fd + (size_t)s * 128);
      float w = wbuf[j];
      acc.x += w * v.x; acc.y += w * v.y; acc.z += w * v.z; acc.w += w * v.w;
    }
    __syncthreads();
  }
  for (int off = 32; off; off >>= 1) psum += __shfl_down(psum, off);
  int wv = t >> 6, ln = t & 63;
  if (ln == 0) red[wv] = psum;
  accbuf[g][t & 31] = acc;
  __syncthreads();
  if (t < 32) {
    float4 a0 = accbuf[0][t], a1 = accbuf[1][t], a2 = accbuf[2][t], a3 = accbuf[3][t];
    float dn = red[0] + red[1];
    float inv = dn > 0.f ? 1.f / dn : 0.f;
    const float* bp = bias + t * 4;
    float4 r;
    r.x = (a0.x + a1.x + a2.x + a3.x) * inv + bp[0];
    r.y = (a0.y + a1.y + a2.y + a3.y) * inv + bp[1];
    r.z = (a0.z + a1.z + a2.z + a3.z) * inv + bp[2];
    r.w = (a0.w + a1.w + a2.w + a3.w) * inv + bp[3];
    *(float4*)&out[(size_t)n * 128 + t * 4] = r;
  }
}

// ---------------- mean-pool: 2-stage ----------------

__global__ void pool_partial_kernel(const float* __restrict__ h2, const int* __restrict__ gid,
                                    float* __restrict__ sums, int N) {
  int g = blockIdx.x / PSPLIT;
  int sp = blockIdx.x % PSPLIT;
  int tid = threadIdx.x;
  int lo0 = 0, hi0 = N;
  while (lo0 < hi0) { int m = (lo0 + hi0) >> 1; if (gid[m] < g) lo0 = m + 1; else hi0 = m; }
  int lo1 = lo0, hi1 = N;
  while (lo1 < hi1) { int m = (lo1 + hi1) >> 1; if (gid[m] < g + 1) lo1 = m + 1; else hi1 = m; }
  float a0 = 0.f, a1 = 0.f, a2 = 0.f, a3 = 0.f;
  int n = lo0 + sp;
  for (; n + 3 * PSPLIT < lo1; n += 4 * PSPLIT) {
    a0 += h2[(size_t)n * 128 + tid];
    a1 += h2[(size_t)(n + PSPLIT) * 128 + tid];
    a2 += h2[(size_t)(n + 2 * PSPLIT) * 128 + tid];
    a3 += h2[(size_t)(n + 3 * PSPLIT) * 128 + tid];
  }
  for (; n < lo1; n += PSPLIT) a0 += h2[(size_t)n * 128 + tid];
  float acc = (a0 + a1) + (a2 + a3);
  atomicAdd(&sums[g * 128 + tid], acc);
}

__global__ void pool_final_kernel(const float* __restrict__ sums, const int* __restrict__ gid,
                                  const float* __restrict__ linW, const float* __restrict__ linb,
                                  float* __restrict__ out, int N) {
  int g = blockIdx.x;
  int tid = threadIdx.x;
  int lo0 = 0, hi0 = N;
  while (lo0 < hi0) { int m = (lo0 + hi0) >> 1; if (gid[m] < g) lo0 = m + 1; else hi0 = m; }
  int lo1 = lo0, hi1 = N;
  while (lo1 < hi1) { int m = (lo1 + hi1) >> 1; if (gid[m] < g + 1) lo1 = m + 1; else hi1 = m; }
  int cnt = lo1 - lo0;
  float hg = sums[g * 128 + tid] / (float)(cnt > 0 ? cnt : 1);
  __shared__ float hgs[128];
  hgs[tid] = hg;
  __syncthreads();
  float o = linb[tid];
#pragma unroll 4
  for (int dd = 0; dd < 128; dd++) o += hgs[dd] * linW[dd * 128 + tid];
  out[g * 128 + tid] = fmaxf(o, 0.f);
}

// ---------------- launch ----------------

extern "C" void kernel_launch(void* const* d_in, const int* in_sizes, int n_in,
                              void* d_out, int out_size, void* d_ws, size_t ws_size,
                              hipStream_t stream) {
  const float* x    = (const float*)d_in[0];
  const int*   src  = (const int*)d_in[1];
  const int*   dst  = (const int*)d_in[2];
  const int*   gid  = (const int*)d_in[3];
  const float* W1   = (const float*)d_in[4];
  const float* al1  = (const float*)d_in[5];
  const float* ar1  = (const float*)d_in[6];
  const float* b1   = (const float*)d_in[7];
  const float* W2   = (const float*)d_in[8];
  const float* al2  = (const float*)d_in[9];
  const float* ar2  = (const float*)d_in[10];
  const float* b2   = (const float*)d_in[11];
  const float* linW = (const float*)d_in[12];
  const float* linb = (const float*)d_in[13];
  float* out = (float*)d_out;

  char* ws = (char*)d_ws;
  size_t off = 0;
  auto alloc = [&](size_t bytes) -> void* {
    void* p = ws + off;
    off += (bytes + 255) & ~(size_t)255;
    return p;
  };
  float* aggx    = (float*)alloc((size_t)NN * 384 * 4);
  float* h1      = (float*)alloc((size_t)NN * 384 * 4);
  float* f2      = (float*)alloc((size_t)NN * 128 * 4);
  float* h2      = (float*)alloc((size_t)NN * 128 * 4);
  float* el1     = (float*)alloc((size_t)NN * 3 * 4);
  float* er1     = (float*)alloc((size_t)NN * 3 * 4);
  float* el2     = (float*)alloc((size_t)NN * 4);
  float* er2     = (float*)alloc((size_t)NN * 4);
  float* wlr     = (float*)alloc((size_t)768 * 4);
  int*   rowptr  = (int*)alloc((size_t)(NN + 1) * 4);
  int*   csr_src = (int*)alloc((size_t)NE * 4);
  int*   bsum    = (int*)alloc((size_t)NSCANB * 4);
  int*   boff    = (int*)alloc((size_t)NSCANB * 4);
  // zero-initialized region (single memset): indeg, cursor, gsums
  int*   indeg   = (int*)alloc((size_t)NN * 4);
  int*   cursor  = (int*)alloc((size_t)NN * 4);
  float* gsums   = (float*)alloc((size_t)NG * 128 * 4);
  (void)ws_size;
  size_t zbytes = (char*)(gsums + NG * 128) - (char*)indeg;
  hipMemsetAsync(indeg, 0, zbytes, stream);

  // CSR build (hierarchical scan)
  hist_kernel<<<(NE + 255) / 256, 256, 0, stream>>>(dst, indeg, NE);
  scan1_kernel<<<NSCANB, 256, 0, stream>>>(indeg, rowptr, bsum, NN);
  scan2_kernel<<<1, 128, 0, stream>>>(bsum, boff, rowptr + NN, NSCANB);
  scan3_kernel<<<NSCANB, 256, 0, stream>>>(rowptr, boff, NN);
  scatter_kernel<<<(NE + 255) / 256, 256, 0, stream>>>(src, dst, rowptr, cursor, csr_src, NE);

  // Layer 1 (x-space): wlr -> el/er -> aggregate x -> per-head GEMM with bias+ELU
  prep_wlr_kernel<<<3, 256, 0, stream>>>(W1, al1, ar1, wlr);
  elr_kernel<<<(NN + 3) / 4, 256, 0, stream>>>(x, wlr, el1, er1, NN);
  aggregate_x_kernel<<<NN, 128, 0, stream>>>(x, el1, er1, rowptr, csr_src, aggx);
  gemm_bcast_kernel<128, 6, true, true><<<NROWT2 * 6, 256, 0, stream>>>(
      aggx, 384, W1, 384, h1, 384, b1);

  // Layer 2: f2 = h1 @ W2 ; el2/er2 ; aggregate(+b2) -> h2
  gemm_bcast_kernel<384, 2, false, false><<<NROWT2 * 2, 256, 0, stream>>>(
      h1, 384, W2, 128, f2, 128, nullptr);
  att_coef_kernel<<<(NN + 3) / 4, 256, 0, stream>>>(f2, al2, ar2, el2, er2, NN);
  aggregate1_kernel<<<NN, 128, 0, stream>>>(f2, el2, er2, b2, rowptr, csr_src, h2);

  // Mean-pool + linear head
  pool_partial_kernel<<<NG * PSPLIT, 128, 0, stream>>>(h2, gid, gsums, NN);
  pool_final_kernel<<<NG, 128, 0, stream>>>(gsums, gid, linW, linb, out, NN);
}

// Round 3
// 307.089 us; speedup vs baseline: 1.6929x; 1.0902x over previous
//
#include <hip/hip_runtime.h>
#include <hip/hip_bf16.h>

#define NN 20000
#define NE 320000
#define NG 16
#define PSPLIT 32
#define NSCANB 79  // ceil(20000/256)

// ---------------- CSR build ----------------

__global__ void hist_kernel(const int* __restrict__ dst, int* __restrict__ indeg, int E) {
  int e = blockIdx.x * 256 + threadIdx.x;
  if (e < E) atomicAdd(&indeg[dst[e]], 1);
}

// hierarchical exclusive scan: per-block scan + block sums
__global__ void scan1_kernel(const int* __restrict__ in, int* __restrict__ outp,
                             int* __restrict__ bsum, int n) {
  int b = blockIdx.x, t = threadIdx.x;
  int i = b * 256 + t;
  int lane = t & 63, wv = t >> 6;
  __shared__ int ws[4];
  int v = (i < n) ? in[i] : 0;
  int x = v;
#pragma unroll
  for (int off = 1; off < 64; off <<= 1) {
    int y = __shfl_up(x, off);
    if (lane >= off) x += y;
  }
  if (lane == 63) ws[wv] = x;
  __syncthreads();
  int add = 0;
  for (int w2 = 0; w2 < wv; w2++) add += ws[w2];
  x += add;
  if (i < n) outp[i] = x - v;  // block-local exclusive
  if (t == 255) bsum[b] = x;   // block total
}

// scan block sums (nb <= 128), write offsets + grand total to rowptr[NN]
__global__ void scan2_kernel(const int* __restrict__ bsum, int* __restrict__ boff,
                             int* __restrict__ rp_end, int nb) {
  int t = threadIdx.x;  // 128
  int lane = t & 63, wv = t >> 6;
  __shared__ int ws[2];
  int v = (t < nb) ? bsum[t] : 0;
  int x = v;
#pragma unroll
  for (int off = 1; off < 64; off <<= 1) {
    int y = __shfl_up(x, off);
    if (lane >= off) x += y;
  }
  if (lane == 63) ws[wv] = x;
  __syncthreads();
  if (wv == 1) x += ws[0];
  if (t < nb) boff[t] = x - v;
  if (t == 127) *rp_end = x;
}

__global__ void scan3_kernel(int* __restrict__ outp, const int* __restrict__ boff, int n) {
  int i = blockIdx.x * 256 + threadIdx.x;
  if (i < n) outp[i] += boff[blockIdx.x];
}

__global__ void scatter_kernel(const int* __restrict__ src, const int* __restrict__ dst,
                               const int* __restrict__ rowptr, int* __restrict__ cursor,
                               int* __restrict__ csr_src, int E) {
  int e = blockIdx.x * 256 + threadIdx.x;
  if (e < E) {
    int d = dst[e];
    int p = atomicAdd(&cursor[d], 1);
    csr_src[rowptr[d] + p] = src[e];
  }
}

// ---------------- layer-1 attention vectors pushed through W1 ----------------

__global__ void prep_wlr_kernel(const float* __restrict__ W1, const float* __restrict__ al1,
                                const float* __restrict__ ar1, float* __restrict__ wlr) {
  int t = blockIdx.x * 256 + threadIdx.x;  // 768 total
  if (t >= 768) return;
  int k = t & 127;
  int j = t >> 7;  // 0..5
  int h = j % 3;
  const float* av = (j < 3 ? al1 : ar1) + h * 128;
  const float* wrow = W1 + (size_t)k * 384 + h * 128;
  float s = 0.f;
#pragma unroll 4
  for (int d = 0; d < 128; d++) s += wrow[d] * av[d];
  wlr[j * 128 + k] = s;
}

// el1/er1 for all nodes: one wave per node
__global__ void elr_kernel(const float* __restrict__ x, const float* __restrict__ wlr,
                           float* __restrict__ el, float* __restrict__ er, int N) {
  __shared__ float wl_s[768];
  int t = threadIdx.x;
  for (int i = t; i < 768; i += 256) wl_s[i] = wlr[i];
  __syncthreads();
  int w = (blockIdx.x * 256 + t) >> 6;
  int lane = t & 63;
  if (w >= N) return;
  float v0 = x[(size_t)w * 128 + lane], v1 = x[(size_t)w * 128 + 64 + lane];
  float s[6];
#pragma unroll
  for (int j = 0; j < 6; j++) s[j] = v0 * wl_s[j * 128 + lane] + v1 * wl_s[j * 128 + 64 + lane];
#pragma unroll
  for (int off = 32; off; off >>= 1)
#pragma unroll
    for (int j = 0; j < 6; j++) s[j] += __shfl_down(s[j], off);
  if (lane == 0) {
    el[w * 3 + 0] = s[0]; el[w * 3 + 1] = s[1]; el[w * 3 + 2] = s[2];
    er[w * 3 + 0] = s[3]; er[w * 3 + 1] = s[4]; er[w * 3 + 2] = s[5];
  }
}

// ---------------- layer-1 aggregation in x-space ----------------

__global__ void aggregate_x_kernel(const float* __restrict__ x, const float* __restrict__ el,
                                   const float* __restrict__ er, const int* __restrict__ rowptr,
                                   const int* __restrict__ csr_src, float* __restrict__ aggx) {
  int n = blockIdx.x;
  int t = threadIdx.x;  // 128
  __shared__ float wbuf[3][128];
  __shared__ int sbuf[128];
  __shared__ float red[6];
  __shared__ float4 accbuf[3][4][32];
  int rs = rowptr[n];
  int deg = rowptr[n + 1] - rs;
  float er0 = er[n * 3 + 0], er1 = er[n * 3 + 1], er2 = er[n * 3 + 2];
  float p0 = 0.f, p1 = 0.f, p2 = 0.f;
  int g = t >> 5, dq = t & 31;
  const float* xd = x + dq * 4;
  float4 a0 = make_float4(0, 0, 0, 0), a1 = a0, a2 = a0;
  for (int base = 0; base < deg; base += 128) {
    int cnt = min(128, deg - base);
    if (t < cnt) {
      int s = csr_src[rs + base + t];
      sbuf[t] = s;
      float e0 = el[s * 3 + 0] + er0, e1 = el[s * 3 + 1] + er1, e2 = el[s * 3 + 2] + er2;
      e0 = e0 > 0.f ? e0 : 0.2f * e0;
      e1 = e1 > 0.f ? e1 : 0.2f * e1;
      e2 = e2 > 0.f ? e2 : 0.2f * e2;
      float w0 = __expf(e0), w1 = __expf(e1), w2 = __expf(e2);
      wbuf[0][t] = w0; wbuf[1][t] = w1; wbuf[2][t] = w2;
      p0 += w0; p1 += w1; p2 += w2;
    }
    __syncthreads();
    int j = g;
    for (; j + 4 < cnt; j += 8) {
      int s0 = sbuf[j], s1 = sbuf[j + 4];
      float4 v0 = *(const float4*)(xd + (size_t)s0 * 128);
      float4 v1 = *(const float4*)(xd + (size_t)s1 * 128);
      float w00 = wbuf[0][j], w01 = wbuf[1][j], w02 = wbuf[2][j];
      float w10 = wbuf[0][j + 4], w11 = wbuf[1][j + 4], w12 = wbuf[2][j + 4];
      a0.x += w00 * v0.x + w10 * v1.x; a0.y += w00 * v0.y + w10 * v1.y;
      a0.z += w00 * v0.z + w10 * v1.z; a0.w += w00 * v0.w + w10 * v1.w;
      a1.x += w01 * v0.x + w11 * v1.x; a1.y += w01 * v0.y + w11 * v1.y;
      a1.z += w01 * v0.z + w11 * v1.z; a1.w += w01 * v0.w + w11 * v1.w;
      a2.x += w02 * v0.x + w12 * v1.x; a2.y += w02 * v0.y + w12 * v1.y;
      a2.z += w02 * v0.z + w12 * v1.z; a2.w += w02 * v0.w + w12 * v1.w;
    }
    for (; j < cnt; j += 4) {
      int s = sbuf[j];
      float4 v = *(const float4*)(xd + (size_t)s * 128);
      float w0 = wbuf[0][j], w1 = wbuf[1][j], w2 = wbuf[2][j];
      a0.x += w0 * v.x; a0.y += w0 * v.y; a0.z += w0 * v.z; a0.w += w0 * v.w;
      a1.x += w1 * v.x; a1.y += w1 * v.y; a1.z += w1 * v.z; a1.w += w1 * v.w;
      a2.x += w2 * v.x; a2.y += w2 * v.y; a2.z += w2 * v.z; a2.w += w2 * v.w;
    }
    __syncthreads();
  }
  for (int off = 32; off; off >>= 1) {
    p0 += __shfl_down(p0, off);
    p1 += __shfl_down(p1, off);
    p2 += __shfl_down(p2, off);
  }
  int wv = t >> 6, ln = t & 63;
  if (ln == 0) { red[wv * 3 + 0] = p0; red[wv * 3 + 1] = p1; red[wv * 3 + 2] = p2; }
  accbuf[0][g][dq] = a0;
  accbuf[1][g][dq] = a1;
  accbuf[2][g][dq] = a2;
  __syncthreads();
  if (t < 96) {
    int h = t >> 5, d = t & 31;
    float4 s0 = accbuf[h][0][d], s1 = accbuf[h][1][d], s2 = accbuf[h][2][d], s3 = accbuf[h][3][d];
    float dn = red[h] + red[3 + h];
    float inv = dn > 0.f ? 1.f / dn : 0.f;
    float4 r;
    r.x = (s0.x + s1.x + s2.x + s3.x) * inv;
    r.y = (s0.y + s1.y + s2.y + s3.y) * inv;
    r.z = (s0.z + s1.z + s2.z + s3.z) * inv;
    r.w = (s0.w + s1.w + s2.w + s3.w) * inv;
    *(float4*)&aggx[(size_t)n * 384 + h * 128 + d * 4] = r;
  }
}

// ---------------- GEMM: 64 rows x 64 cols per block, 256 threads, single-LDS-buffer
// software pipeline (T14 async-split):
//   writeLDS(t) -> barrier -> issue global loads(t+1) to regs -> compute(t) -> barrier
// The prefetch latency (~200-700cy L2/L3) hides under the 1024-cycle compute phase;
// the vmcnt wait lands at the next iteration's ds_write. Round-2 post-mortem: with
// stage->barrier->compute and 1.2 blocks/CU, every K-tile exposed the full global
// latency (VALUBusy 14%). 64-row tiles also give 1878/626 blocks (7.3/2.4 per CU).
// Wave w owns cols [cb*64+w*16,+16) -> B LDS reads are wave-uniform BROADCASTS
// (0 conflicts, proven round 2). Thread owns row `lane`; A-fragment = one contiguous
// ds_read_b128 (4 k's). A staged as [q][r^q] float4 planes: write and read both
// cover all 8 bank-quads per 8-lane group (conflict-free, re-derived for 64 rows).

#define NROWT64 313  // ceil(20000/64)

template <int K, int NCB, bool HEADS, bool BIAS_ELU>
__launch_bounds__(256, 4)
__global__ void gemm_db_kernel(const float* __restrict__ A, int lda,
                               const float* __restrict__ B, int ldb,
                               float* __restrict__ C, int ldc,
                               const float* __restrict__ bias) {
  __shared__ float4 As[8 * 64];   // [q][r^q], 8 KB
  __shared__ float4 Bs[32 * 16];  // [kk][n4], 8 KB
  int t = threadIdx.x;
  int lane = t & 63;
  int w = t >> 6;

  // bijective XCD-chunk swizzle: consecutive logical tiles -> same XCD L2.
  constexpr int NWG = NROWT64 * NCB;
  constexpr int QW = NWG >> 3, RW = NWG & 7;
  int o = blockIdx.x;
  int xcd = o & 7, i8 = o >> 3;
  int wgid = (xcd < RW ? xcd * (QW + 1) : RW * (QW + 1) + (xcd - RW) * QW) + i8;
  int rt = wgid / NCB;
  int cb = wgid - rt * NCB;
  int m0 = rt * 64;
  int cbase = cb * 64;
  int col0 = cbase + w * 16;
  const float* Ab = A + (HEADS ? (size_t)(cb >> 1) * 128 : 0);

  // staging geometry (fixed across K-tiles; only the k-offset advances)
  int r0 = t >> 3, q0 = t & 7;  // plane p=0 covers rows 0..31, p=1 rows 32..63 (same q)
  int rowA0 = m0 + r0;          if (rowA0 >= NN) rowA0 = NN - 1;
  int rowA1 = m0 + r0 + 32;     if (rowA1 >= NN) rowA1 = NN - 1;
  const float* srcA0 = Ab + (size_t)rowA0 * lda + q0 * 4;
  const float* srcA1 = Ab + (size_t)rowA1 * lda + q0 * 4;
  int dstA0 = q0 * 64 + (r0 ^ q0);
  int dstA1 = q0 * 64 + ((r0 + 32) ^ q0);  // == (r0^q0)+32
  int kkB = t >> 4, nfB = t & 15;
  const float* srcB0 = B + (size_t)kkB * ldb + cbase + nfB * 4;
  const float* srcB1 = B + (size_t)(kkB + 16) * ldb + cbase + nfB * 4;
  int dstB0 = kkB * 16 + nfB;
  int dstB1 = (kkB + 16) * 16 + nfB;

  float acc[16];
#pragma unroll
  for (int c = 0; c < 16; ++c) acc[c] = 0.f;

  // prologue: load tile 0 into regs
  float4 ra0 = *(const float4*)srcA0;
  float4 ra1 = *(const float4*)srcA1;
  float4 rb0 = *(const float4*)srcB0;
  float4 rb1 = *(const float4*)srcB1;

  constexpr int NT = K / 32;
  for (int tk = 0; tk < NT; ++tk) {
    // write staged tile to LDS (vmcnt wait lands here, loads long since arrived)
    As[dstA0] = ra0;
    As[dstA1] = ra1;
    Bs[dstB0] = rb0;
    Bs[dstB1] = rb1;
    __syncthreads();
    // issue next tile's loads NOW; latency hides under the compute below
    if (tk + 1 < NT) {
      int ko = (tk + 1) * 32;
      ra0 = *(const float4*)(srcA0 + ko);
      ra1 = *(const float4*)(srcA1 + ko);
      rb0 = *(const float4*)(srcB0 + (size_t)ko * ldb);
      rb1 = *(const float4*)(srcB1 + (size_t)ko * ldb);
    }
    // compute 64x16 per wave from LDS
#pragma unroll
    for (int q = 0; q < 8; ++q) {
      float4 a4 = As[q * 64 + (lane ^ q)];
      float af[4] = {a4.x, a4.y, a4.z, a4.w};
#pragma unroll
      for (int j = 0; j < 4; ++j) {
        const float4* Bq = &Bs[(q * 4 + j) * 16 + (w << 2)];  // wave-uniform: broadcast
        float4 b0 = Bq[0], b1 = Bq[1], b2 = Bq[2], b3 = Bq[3];
        float bf[16] = {b0.x, b0.y, b0.z, b0.w, b1.x, b1.y, b1.z, b1.w,
                        b2.x, b2.y, b2.z, b2.w, b3.x, b3.y, b3.z, b3.w};
        float aj = af[j];
#pragma unroll
        for (int c = 0; c < 16; ++c) acc[c] += aj * bf[c];
      }
    }
    __syncthreads();
  }

  int row = m0 + lane;
  if (row < NN) {
    float* Cr = C + (size_t)row * ldc + col0;
#pragma unroll
    for (int cc = 0; cc < 4; ++cc) {
      float4 v = make_float4(acc[cc * 4 + 0], acc[cc * 4 + 1],
                             acc[cc * 4 + 2], acc[cc * 4 + 3]);
      if (BIAS_ELU) {
        const float* bp = bias + col0 + cc * 4;
        v.x += bp[0]; v.y += bp[1]; v.z += bp[2]; v.w += bp[3];
        v.x = v.x > 0.f ? v.x : expm1f(v.x);
        v.y = v.y > 0.f ? v.y : expm1f(v.y);
        v.z = v.z > 0.f ? v.z : expm1f(v.z);
        v.w = v.w > 0.f ? v.w : expm1f(v.w);
      }
      *(float4*)(Cr + cc * 4) = v;
    }
  }
}

// ---------------- attention coefficients (layer 2, H=1, reads f2) ----------------

__global__ void att_coef_kernel(const float* __restrict__ f, const float* __restrict__ al,
                                const float* __restrict__ ar, float* __restrict__ el,
                                float* __restrict__ er, int NH) {
  int w = (blockIdx.x * 256 + threadIdx.x) >> 6;
  int lane = threadIdx.x & 63;
  if (w >= NH) return;
  const float* fr = f + (size_t)w * 128;
  float v0 = fr[lane], v1 = fr[64 + lane];
  float a0 = al[lane], a1 = al[64 + lane];
  float r0 = ar[lane], r1 = ar[64 + lane];
  float se = v0 * a0 + v1 * a1;
  float sr = v0 * r0 + v1 * r1;
  for (int off = 32; off; off >>= 1) {
    se += __shfl_down(se, off);
    sr += __shfl_down(sr, off);
  }
  if (lane == 0) { el[w] = se; er[w] = sr; }
}

// ---------------- layer-2 aggregation (H=1, gathers f2) ----------------

__global__ void aggregate1_kernel(const float* __restrict__ f, const float* __restrict__ el,
                                  const float* __restrict__ er, const float* __restrict__ bias,
                                  const int* __restrict__ rowptr, const int* __restrict__ csr_src,
                                  float* __restrict__ out) {
  int n = blockIdx.x;
  int t = threadIdx.x;
  __shared__ float wbuf[128];
  __shared__ int sbuf[128];
  __shared__ float red[2];
  __shared__ float4 accbuf[4][32];
  int rs = rowptr[n];
  int deg = rowptr[n + 1] - rs;
  float ern = er[n];
  float psum = 0.f;
  int g = t >> 5;
  int d = (t & 31) * 4;
  const float* fd = f + d;
  float4 acc = make_float4(0.f, 0.f, 0.f, 0.f);
  for (int base = 0; base < deg; base += 128) {
    int cnt = min(128, deg - base);
    if (t < cnt) {
      int s = csr_src[rs + base + t];
      sbuf[t] = s;
      float e = el[s] + ern;
      e = e > 0.f ? e : 0.2f * e;
      float w = __expf(e);
      wbuf[t] = w;
      psum += w;
    }
    __syncthreads();
    int j = g;
    for (; j + 4 < cnt; j += 8) {
      int s0 = sbuf[j], s1 = sbuf[j + 4];
      float4 v0 = *(const float4*)(fd + (size_t)s0 * 128);
      float4 v1 = *(const float4*)(fd + (size_t)s1 * 128);
      float w0 = wbuf[j], w1 = wbuf[j + 4];
      acc.x += w0 * v0.x + w1 * v1.x;
      acc.y += w0 * v0.y + w1 * v1.y;
      acc.z += w0 * v0.z + w1 * v1.z;
      acc.w += w0 * v0.w + w1 * v1.w;
    }
    for (; j < cnt; j += 4) {
      int s = sbuf[j];
      float4 v = *(const float4*)(fd + (size_t)s * 128);
      float w = wbuf[j];
      acc.x += w * v.x; acc.y += w * v.y; acc.z += w * v.z; acc.w += w * v.w;
    }
    __syncthreads();
  }
  for (int off = 32; off; off >>= 1) psum += __shfl_down(psum, off);
  int wv = t >> 6, ln = t & 63;
  if (ln == 0) red[wv] = psum;
  accbuf[g][t & 31] = acc;
  __syncthreads();
  if (t < 32) {
    float4 a0 = accbuf[0][t], a1 = accbuf[1][t], a2 = accbuf[2][t], a3 = accbuf[3][t];
    float dn = red[0] + red[1];
    float inv = dn > 0.f ? 1.f / dn : 0.f;
    const float* bp = bias + t * 4;
    float4 r;
    r.x = (a0.x + a1.x + a2.x + a3.x) * inv + bp[0];
    r.y = (a0.y + a1.y + a2.y + a3.y) * inv + bp[1];
    r.z = (a0.z + a1.z + a2.z + a3.z) * inv + bp[2];
    r.w = (a0.w + a1.w + a2.w + a3.w) * inv + bp[3];
    *(float4*)&out[(size_t)n * 128 + t * 4] = r;
  }
}

// ---------------- mean-pool: 2-stage ----------------

__global__ void pool_partial_kernel(const float* __restrict__ h2, const int* __restrict__ gid,
                                    float* __restrict__ sums, int N) {
  int g = blockIdx.x / PSPLIT;
  int sp = blockIdx.x % PSPLIT;
  int tid = threadIdx.x;
  int lo0 = 0, hi0 = N;
  while (lo0 < hi0) { int m = (lo0 + hi0) >> 1; if (gid[m] < g) lo0 = m + 1; else hi0 = m; }
  int lo1 = lo0, hi1 = N;
  while (lo1 < hi1) { int m = (lo1 + hi1) >> 1; if (gid[m] < g + 1) lo1 = m + 1; else hi1 = m; }
  float a0 = 0.f, a1 = 0.f, a2 = 0.f, a3 = 0.f;
  int n = lo0 + sp;
  for (; n + 3 * PSPLIT < lo1; n += 4 * PSPLIT) {
    a0 += h2[(size_t)n * 128 + tid];
    a1 += h2[(size_t)(n + PSPLIT) * 128 + tid];
    a2 += h2[(size_t)(n + 2 * PSPLIT) * 128 + tid];
    a3 += h2[(size_t)(n + 3 * PSPLIT) * 128 + tid];
  }
  for (; n < lo1; n += PSPLIT) a0 += h2[(size_t)n * 128 + tid];
  float acc = (a0 + a1) + (a2 + a3);
  atomicAdd(&sums[g * 128 + tid], acc);
}

__global__ void pool_final_kernel(const float* __restrict__ sums, const int* __restrict__ gid,
                                  const float* __restrict__ linW, const float* __restrict__ linb,
                                  float* __restrict__ out, int N) {
  int g = blockIdx.x;
  int tid = threadIdx.x;
  int lo0 = 0, hi0 = N;
  while (lo0 < hi0) { int m = (lo0 + hi0) >> 1; if (gid[m] < g) lo0 = m + 1; else hi0 = m; }
  int lo1 = lo0, hi1 = N;
  while (lo1 < hi1) { int m = (lo1 + hi1) >> 1; if (gid[m] < g + 1) lo1 = m + 1; else hi1 = m; }
  int cnt = lo1 - lo0;
  float hg = sums[g * 128 + tid] / (float)(cnt > 0 ? cnt : 1);
  __shared__ float hgs[128];
  hgs[tid] = hg;
  __syncthreads();
  float o = linb[tid];
#pragma unroll 4
  for (int dd = 0; dd < 128; dd++) o += hgs[dd] * linW[dd * 128 + tid];
  out[g * 128 + tid] = fmaxf(o, 0.f);
}

// ---------------- launch ----------------

extern "C" void kernel_launch(void* const* d_in, const int* in_sizes, int n_in,
                              void* d_out, int out_size, void* d_ws, size_t ws_size,
                              hipStream_t stream) {
  const float* x    = (const float*)d_in[0];
  const int*   src  = (const int*)d_in[1];
  const int*   dst  = (const int*)d_in[2];
  const int*   gid  = (const int*)d_in[3];
  const float* W1   = (const float*)d_in[4];
  const float* al1  = (const float*)d_in[5];
  const float* ar1  = (const float*)d_in[6];
  const float* b1   = (const float*)d_in[7];
  const float* W2   = (const float*)d_in[8];
  const float* al2  = (const float*)d_in[9];
  const float* ar2  = (const float*)d_in[10];
  const float* b2   = (const float*)d_in[11];
  const float* linW = (const float*)d_in[12];
  const float* linb = (const float*)d_in[13];
  float* out = (float*)d_out;

  char* ws = (char*)d_ws;
  size_t off = 0;
  auto alloc = [&](size_t bytes) -> void* {
    void* p = ws + off;
    off += (bytes + 255) & ~(size_t)255;
    return p;
  };
  float* aggx    = (float*)alloc((size_t)NN * 384 * 4);
  float* h1      = (float*)alloc((size_t)NN * 384 * 4);
  float* f2      = (float*)alloc((size_t)NN * 128 * 4);
  float* h2      = (float*)alloc((size_t)NN * 128 * 4);
  float* el1     = (float*)alloc((size_t)NN * 3 * 4);
  float* er1     = (float*)alloc((size_t)NN * 3 * 4);
  float* el2     = (float*)alloc((size_t)NN * 4);
  float* er2     = (float*)alloc((size_t)NN * 4);
  float* wlr     = (float*)alloc((size_t)768 * 4);
  int*   rowptr  = (int*)alloc((size_t)(NN + 1) * 4);
  int*   csr_src = (int*)alloc((size_t)NE * 4);
  int*   bsum    = (int*)alloc((size_t)NSCANB * 4);
  int*   boff    = (int*)alloc((size_t)NSCANB * 4);
  // zero-initialized region (single memset): indeg, cursor, gsums
  int*   indeg   = (int*)alloc((size_t)NN * 4);
  int*   cursor  = (int*)alloc((size_t)NN * 4);
  float* gsums   = (float*)alloc((size_t)NG * 128 * 4);
  (void)ws_size;
  size_t zbytes = (char*)(gsums + NG * 128) - (char*)indeg;
  hipMemsetAsync(indeg, 0, zbytes, stream);

  // CSR build (hierarchical scan)
  hist_kernel<<<(NE + 255) / 256, 256, 0, stream>>>(dst, indeg, NE);
  scan1_kernel<<<NSCANB, 256, 0, stream>>>(indeg, rowptr, bsum, NN);
  scan2_kernel<<<1, 128, 0, stream>>>(bsum, boff, rowptr + NN, NSCANB);
  scan3_kernel<<<NSCANB, 256, 0, stream>>>(rowptr, boff, NN);
  scatter_kernel<<<(NE + 255) / 256, 256, 0, stream>>>(src, dst, rowptr, cursor, csr_src, NE);

  // Layer 1 (x-space): wlr -> el/er -> aggregate x -> per-head GEMM with bias+ELU
  prep_wlr_kernel<<<3, 256, 0, stream>>>(W1, al1, ar1, wlr);
  elr_kernel<<<(NN + 3) / 4, 256, 0, stream>>>(x, wlr, el1, er1, NN);
  aggregate_x_kernel<<<NN, 128, 0, stream>>>(x, el1, er1, rowptr, csr_src, aggx);
  gemm_db_kernel<128, 6, true, true><<<NROWT64 * 6, 256, 0, stream>>>(
      aggx, 384, W1, 384, h1, 384, b1);

  // Layer 2: f2 = h1 @ W2 ; el2/er2 ; aggregate(+b2) -> h2
  gemm_db_kernel<384, 2, false, false><<<NROWT64 * 2, 256, 0, stream>>>(
      h1, 384, W2, 128, f2, 128, nullptr);
  att_coef_kernel<<<(NN + 3) / 4, 256, 0, stream>>>(f2, al2, ar2, el2, er2, NN);
  aggregate1_kernel<<<NN, 128, 0, stream>>>(f2, el2, er2, b2, rowptr, csr_src, h2);

  // Mean-pool + linear head
  pool_partial_kernel<<<NG * PSPLIT, 128, 0, stream>>>(h2, gid, gsums, NN);
  pool_final_kernel<<<NG, 128, 0, stream>>>(gsums, gid, linW, linb, out, NN);
}

// Round 5
// 306.395 us; speedup vs baseline: 1.6967x; 1.0023x over previous
//
#include <hip/hip_runtime.h>
#include <hip/hip_bf16.h>

#define NN 20000
#define NE 320000
#define NG 16
#define PSPLIT 32
#define NSCANB 79  // ceil(20000/256)

// ---------------- CSR build ----------------

__global__ void hist_kernel(const int* __restrict__ dst, int* __restrict__ indeg, int E) {
  int e = blockIdx.x * 256 + threadIdx.x;
  if (e < E) atomicAdd(&indeg[dst[e]], 1);
}

// hierarchical exclusive scan: per-block scan + block sums
__global__ void scan1_kernel(const int* __restrict__ in, int* __restrict__ outp,
                             int* __restrict__ bsum, int n) {
  int b = blockIdx.x, t = threadIdx.x;
  int i = b * 256 + t;
  int lane = t & 63, wv = t >> 6;
  __shared__ int ws[4];
  int v = (i < n) ? in[i] : 0;
  int x = v;
#pragma unroll
  for (int off = 1; off < 64; off <<= 1) {
    int y = __shfl_up(x, off);
    if (lane >= off) x += y;
  }
  if (lane == 63) ws[wv] = x;
  __syncthreads();
  int add = 0;
  for (int w2 = 0; w2 < wv; w2++) add += ws[w2];
  x += add;
  if (i < n) outp[i] = x - v;  // block-local exclusive
  if (t == 255) bsum[b] = x;   // block total
}

// scan block sums (nb <= 128), write offsets + grand total to rowptr[NN]
__global__ void scan2_kernel(const int* __restrict__ bsum, int* __restrict__ boff,
                             int* __restrict__ rp_end, int nb) {
  int t = threadIdx.x;  // 128
  int lane = t & 63, wv = t >> 6;
  __shared__ int ws[2];
  int v = (t < nb) ? bsum[t] : 0;
  int x = v;
#pragma unroll
  for (int off = 1; off < 64; off <<= 1) {
    int y = __shfl_up(x, off);
    if (lane >= off) x += y;
  }
  if (lane == 63) ws[wv] = x;
  __syncthreads();
  if (wv == 1) x += ws[0];
  if (t < nb) boff[t] = x - v;
  if (t == 127) *rp_end = x;
}

__global__ void scan3_kernel(int* __restrict__ outp, const int* __restrict__ boff, int n) {
  int i = blockIdx.x * 256 + threadIdx.x;
  if (i < n) outp[i] += boff[blockIdx.x];
}

__global__ void scatter_kernel(const int* __restrict__ src, const int* __restrict__ dst,
                               const int* __restrict__ rowptr, int* __restrict__ cursor,
                               int* __restrict__ csr_src, int E) {
  int e = blockIdx.x * 256 + threadIdx.x;
  if (e < E) {
    int d = dst[e];
    int p = atomicAdd(&cursor[d], 1);
    csr_src[rowptr[d] + p] = src[e];
  }
}

// ---------------- layer-1 attention vectors pushed through W1 ----------------

__global__ void prep_wlr_kernel(const float* __restrict__ W1, const float* __restrict__ al1,
                                const float* __restrict__ ar1, float* __restrict__ wlr) {
  int t = blockIdx.x * 256 + threadIdx.x;  // 768 total
  if (t >= 768) return;
  int k = t & 127;
  int j = t >> 7;  // 0..5
  int h = j % 3;
  const float* av = (j < 3 ? al1 : ar1) + h * 128;
  const float* wrow = W1 + (size_t)k * 384 + h * 128;
  float s = 0.f;
#pragma unroll 4
  for (int d = 0; d < 128; d++) s += wrow[d] * av[d];
  wlr[j * 128 + k] = s;
}

// el1/er1 for all nodes: one wave per node
__global__ void elr_kernel(const float* __restrict__ x, const float* __restrict__ wlr,
                           float* __restrict__ el, float* __restrict__ er, int N) {
  __shared__ float wl_s[768];
  int t = threadIdx.x;
  for (int i = t; i < 768; i += 256) wl_s[i] = wlr[i];
  __syncthreads();
  int w = (blockIdx.x * 256 + t) >> 6;
  int lane = t & 63;
  if (w >= N) return;
  float v0 = x[(size_t)w * 128 + lane], v1 = x[(size_t)w * 128 + 64 + lane];
  float s[6];
#pragma unroll
  for (int j = 0; j < 6; j++) s[j] = v0 * wl_s[j * 128 + lane] + v1 * wl_s[j * 128 + 64 + lane];
#pragma unroll
  for (int off = 32; off; off >>= 1)
#pragma unroll
    for (int j = 0; j < 6; j++) s[j] += __shfl_down(s[j], off);
  if (lane == 0) {
    el[w * 3 + 0] = s[0]; el[w * 3 + 1] = s[1]; el[w * 3 + 2] = s[2];
    er[w * 3 + 0] = s[3]; er[w * 3 + 1] = s[4]; er[w * 3 + 2] = s[5];
  }
}

// ---------------- layer-1 aggregation in x-space ----------------

__global__ void aggregate_x_kernel(const float* __restrict__ x, const float* __restrict__ el,
                                   const float* __restrict__ er, const int* __restrict__ rowptr,
                                   const int* __restrict__ csr_src, float* __restrict__ aggx) {
  int n = blockIdx.x;
  int t = threadIdx.x;  // 128
  __shared__ float wbuf[3][128];
  __shared__ int sbuf[128];
  __shared__ float red[6];
  __shared__ float4 accbuf[3][4][32];
  int rs = rowptr[n];
  int deg = rowptr[n + 1] - rs;
  float er0 = er[n * 3 + 0], er1 = er[n * 3 + 1], er2 = er[n * 3 + 2];
  float p0 = 0.f, p1 = 0.f, p2 = 0.f;
  int g = t >> 5, dq = t & 31;
  const float* xd = x + dq * 4;
  float4 a0 = make_float4(0, 0, 0, 0), a1 = a0, a2 = a0;
  for (int base = 0; base < deg; base += 128) {
    int cnt = min(128, deg - base);
    if (t < cnt) {
      int s = csr_src[rs + base + t];
      sbuf[t] = s;
      float e0 = el[s * 3 + 0] + er0, e1 = el[s * 3 + 1] + er1, e2 = el[s * 3 + 2] + er2;
      e0 = e0 > 0.f ? e0 : 0.2f * e0;
      e1 = e1 > 0.f ? e1 : 0.2f * e1;
      e2 = e2 > 0.f ? e2 : 0.2f * e2;
      float w0 = __expf(e0), w1 = __expf(e1), w2 = __expf(e2);
      wbuf[0][t] = w0; wbuf[1][t] = w1; wbuf[2][t] = w2;
      p0 += w0; p1 += w1; p2 += w2;
    }
    __syncthreads();
    int j = g;
    for (; j + 4 < cnt; j += 8) {
      int s0 = sbuf[j], s1 = sbuf[j + 4];
      float4 v0 = *(const float4*)(xd + (size_t)s0 * 128);
      float4 v1 = *(const float4*)(xd + (size_t)s1 * 128);
      float w00 = wbuf[0][j], w01 = wbuf[1][j], w02 = wbuf[2][j];
      float w10 = wbuf[0][j + 4], w11 = wbuf[1][j + 4], w12 = wbuf[2][j + 4];
      a0.x += w00 * v0.x + w10 * v1.x; a0.y += w00 * v0.y + w10 * v1.y;
      a0.z += w00 * v0.z + w10 * v1.z; a0.w += w00 * v0.w + w10 * v1.w;
      a1.x += w01 * v0.x + w11 * v1.x; a1.y += w01 * v0.y + w11 * v1.y;
      a1.z += w01 * v0.z + w11 * v1.z; a1.w += w01 * v0.w + w11 * v1.w;
      a2.x += w02 * v0.x + w12 * v1.x; a2.y += w02 * v0.y + w12 * v1.y;
      a2.z += w02 * v0.z + w12 * v1.z; a2.w += w02 * v0.w + w12 * v1.w;
    }
    for (; j < cnt; j += 4) {
      int s = sbuf[j];
      float4 v = *(const float4*)(xd + (size_t)s * 128);
      float w0 = wbuf[0][j], w1 = wbuf[1][j], w2 = wbuf[2][j];
      a0.x += w0 * v.x; a0.y += w0 * v.y; a0.z += w0 * v.z; a0.w += w0 * v.w;
      a1.x += w1 * v.x; a1.y += w1 * v.y; a1.z += w1 * v.z; a1.w += w1 * v.w;
      a2.x += w2 * v.x; a2.y += w2 * v.y; a2.z += w2 * v.z; a2.w += w2 * v.w;
    }
    __syncthreads();
  }
  for (int off = 32; off; off >>= 1) {
    p0 += __shfl_down(p0, off);
    p1 += __shfl_down(p1, off);
    p2 += __shfl_down(p2, off);
  }
  int wv = t >> 6, ln = t & 63;
  if (ln == 0) { red[wv * 3 + 0] = p0; red[wv * 3 + 1] = p1; red[wv * 3 + 2] = p2; }
  accbuf[0][g][dq] = a0;
  accbuf[1][g][dq] = a1;
  accbuf[2][g][dq] = a2;
  __syncthreads();
  if (t < 96) {
    int h = t >> 5, d = t & 31;
    float4 s0 = accbuf[h][0][d], s1 = accbuf[h][1][d], s2 = accbuf[h][2][d], s3 = accbuf[h][3][d];
    float dn = red[h] + red[3 + h];
    float inv = dn > 0.f ? 1.f / dn : 0.f;
    float4 r;
    r.x = (s0.x + s1.x + s2.x + s3.x) * inv;
    r.y = (s0.y + s1.y + s2.y + s3.y) * inv;
    r.z = (s0.z + s1.z + s2.z + s3.z) * inv;
    r.w = (s0.w + s1.w + s2.w + s3.w) * inv;
    *(float4*)&aggx[(size_t)n * 384 + h * 128 + d * 4] = r;
  }
}

// ---------------- GEMM: 128x128 tile, 256 threads, 8x8 microtile ----------------
// Round-3 post-mortem: the 1x16 microtile issued 136 ds_read_b128 per 32k-tile per
// thread vs 1024 VALU-cyc of FMA -> LDS pipe ceiling f<=0.2 (measured 23%). The 8x8
// microtile reads 128 b128 per tile against 4096 VALU-cyc -> f<=~0.67.
// Thread (tm=t>>4, tn=t&15) owns rows m0+tm+16i (i=0..7) and cols cb*128 +
// {tn*4..+3, 64+tn*4..+3}.
// As4[r*9+kq] float4 (=A[r][4kq..+3]), row stride 9 (==1 mod 8): staging writes put
// 8 lanes on each bank-quad (bus floor, no conflict); frag reads are 4-address
// 16-lane broadcasts on 4 distinct quads. Bs4[k*33+n4] (=B[k][4n4..+3]): writes are
// contiguous 512B rows; reads 16-address 4-lane broadcasts, 2 words/bank.
// Reg-prefetch pipeline kept from round 3 (writeLDS -> barrier -> prefetch next ->
// compute): compute is 4096 cyc/tile, covers the global latency even at 2 blocks/CU.
// SPLIT (GEMM2): K-split x3 over cb; A col-slice cb*128, B row-slice cb*128,
// C = partial buffer cb (combined in att_combine_kernel). GEMM1: cb = head/col-block.

template <int NCB, bool SPLIT, bool BIAS_ELU>
__launch_bounds__(256, 2)
__global__ void gemm_8x8_kernel(const float* __restrict__ A, int lda,
                                const float* __restrict__ B, int ldb,
                                float* __restrict__ C, int ldc,
                                const float* __restrict__ bias) {
  __shared__ float4 As4[128 * 9];  // 18 KB
  __shared__ float4 Bs4[32 * 33];  // 16.9 KB
  int t = threadIdx.x;
  int tm = t >> 4, tn = t & 15;

  // bijective XCD-chunk swizzle: consecutive logical tiles -> same XCD L2.
  constexpr int NROWT = 157;  // ceil(20000/128)
  constexpr int NWG = NROWT * NCB;
  constexpr int QW = NWG >> 3, RW = NWG & 7;
  int o = blockIdx.x;
  int xcd = o & 7, i8 = o >> 3;
  int wgid = (xcd < RW ? xcd * (QW + 1) : RW * (QW + 1) + (xcd - RW) * QW) + i8;
  int rt = wgid / NCB, cb = wgid - rt * NCB;
  int m0 = rt * 128;

  const float* Ab = A + (size_t)(cb * 128);
  const float* Bb = SPLIT ? B + (size_t)(cb * 128) * ldb : B + cb * 128;
  float* Cb = SPLIT ? C + (size_t)cb * NN * ldc : C + cb * 128;

  // staging geometry (fixed; k-offset advances)
  const float* sA[4];
  int dA[4];
#pragma unroll
  for (int p = 0; p < 4; ++p) {
    int r = p * 32 + (t >> 3);
    int row = m0 + r;
    if (row >= NN) row = NN - 1;  // tail: clamp (stores guarded)
    sA[p] = Ab + (size_t)row * lda + (t & 7) * 4;
    dA[p] = r * 9 + (t & 7);
  }
  const float* sB[4];
  int dB[4];
#pragma unroll
  for (int p = 0; p < 4; ++p) {
    int kk = p * 8 + (t >> 5);
    sB[p] = Bb + (size_t)kk * ldb + (t & 31) * 4;
    dB[p] = kk * 33 + (t & 31);
  }

  float acc[8][8];
#pragma unroll
  for (int i = 0; i < 8; ++i)
#pragma unroll
    for (int c = 0; c < 8; ++c) acc[i][c] = 0.f;

  // prologue: prefetch tile 0
  float4 pa[4], pb[4];
#pragma unroll
  for (int p = 0; p < 4; ++p) {
    pa[p] = *(const float4*)sA[p];
    pb[p] = *(const float4*)sB[p];
  }

  constexpr int NT = 4;  // K=128 per block, 32-k tiles
  for (int tk = 0; tk < NT; ++tk) {
#pragma unroll
    for (int p = 0; p < 4; ++p) {
      As4[dA[p]] = pa[p];
      Bs4[dB[p]] = pb[p];
    }
    __syncthreads();
    if (tk + 1 < NT) {
      int ko = (tk + 1) * 32;
#pragma unroll
      for (int p = 0; p < 4; ++p) {
        pa[p] = *(const float4*)(sA[p] + ko);
        pb[p] = *(const float4*)(sB[p] + (size_t)ko * ldb);
      }
    }
#pragma unroll
    for (int q = 0; q < 8; ++q) {
      float4 fa[8];
#pragma unroll
      for (int i = 0; i < 8; ++i) fa[i] = As4[(tm + 16 * i) * 9 + q];
#pragma unroll
      for (int j = 0; j < 4; ++j) {
        float4 b0 = Bs4[(4 * q + j) * 33 + tn];
        float4 b1 = Bs4[(4 * q + j) * 33 + 16 + tn];
#pragma unroll
        for (int i = 0; i < 8; ++i) {
          float a = (j == 0) ? fa[i].x : (j == 1) ? fa[i].y : (j == 2) ? fa[i].z : fa[i].w;
          acc[i][0] += a * b0.x; acc[i][1] += a * b0.y;
          acc[i][2] += a * b0.z; acc[i][3] += a * b0.w;
          acc[i][4] += a * b1.x; acc[i][5] += a * b1.y;
          acc[i][6] += a * b1.z; acc[i][7] += a * b1.w;
        }
      }
    }
    __syncthreads();
  }

  const float* bp0 = bias ? bias + cb * 128 + tn * 4 : nullptr;
#pragma unroll
  for (int i = 0; i < 8; ++i) {
    int row = m0 + tm + 16 * i;
    if (row < NN) {
      float* Cr = Cb + (size_t)row * ldc + tn * 4;
      float4 v0 = make_float4(acc[i][0], acc[i][1], acc[i][2], acc[i][3]);
      float4 v1 = make_float4(acc[i][4], acc[i][5], acc[i][6], acc[i][7]);
      if (BIAS_ELU) {
        v0.x += bp0[0]; v0.y += bp0[1]; v0.z += bp0[2]; v0.w += bp0[3];
        v1.x += bp0[64]; v1.y += bp0[65]; v1.z += bp0[66]; v1.w += bp0[67];
        v0.x = v0.x > 0.f ? v0.x : expm1f(v0.x);
        v0.y = v0.y > 0.f ? v0.y : expm1f(v0.y);
        v0.z = v0.z > 0.f ? v0.z : expm1f(v0.z);
        v0.w = v0.w > 0.f ? v0.w : expm1f(v0.w);
        v1.x = v1.x > 0.f ? v1.x : expm1f(v1.x);
        v1.y = v1.y > 0.f ? v1.y : expm1f(v1.y);
        v1.z = v1.z > 0.f ? v1.z : expm1f(v1.z);
        v1.w = v1.w > 0.f ? v1.w : expm1f(v1.w);
      }
      *(float4*)Cr = v0;
      *(float4*)(Cr + 64) = v1;
    }
  }
}

// ---------------- combine K-split partials + attention coefficients (layer 2) ----

__global__ void att_combine_kernel(const float* __restrict__ fp, const float* __restrict__ al,
                                   const float* __restrict__ ar, float* __restrict__ f2,
                                   float* __restrict__ el, float* __restrict__ er, int N) {
  int w = (blockIdx.x * 256 + threadIdx.x) >> 6;
  int lane = threadIdx.x & 63;
  if (w >= N) return;
  size_t base = (size_t)w * 128;
  const size_t PS = (size_t)NN * 128;
  float v0 = fp[base + lane] + fp[PS + base + lane] + fp[2 * PS + base + lane];
  float v1 = fp[base + 64 + lane] + fp[PS + base + 64 + lane] + fp[2 * PS + base + 64 + lane];
  f2[base + lane] = v0;
  f2[base + 64 + lane] = v1;
  float se = v0 * al[lane] + v1 * al[64 + lane];
  float sr = v0 * ar[lane] + v1 * ar[64 + lane];
  for (int off = 32; off; off >>= 1) {
    se += __shfl_down(se, off);
    sr += __shfl_down(sr, off);
  }
  if (lane == 0) { el[w] = se; er[w] = sr; }
}

// ---------------- layer-2 aggregation (H=1, gathers f2) ----------------

__global__ void aggregate1_kernel(const float* __restrict__ f, const float* __restrict__ el,
                                  const float* __restrict__ er, const float* __restrict__ bias,
                                  const int* __restrict__ rowptr, const int* __restrict__ csr_src,
                                  float* __restrict__ out) {
  int n = blockIdx.x;
  int t = threadIdx.x;
  __shared__ float wbuf[128];
  __shared__ int sbuf[128];
  __shared__ float red[2];
  __shared__ float4 accbuf[4][32];
  int rs = rowptr[n];
  int deg = rowptr[n + 1] - rs;
  float ern = er[n];
  float psum = 0.f;
  int g = t >> 5;
  int d = (t & 31) * 4;
  const float* fd = f + d;
  float4 acc = make_float4(0.f, 0.f, 0.f, 0.f);
  for (int base = 0; base < deg; base += 128) {
    int cnt = min(128, deg - base);
    if (t < cnt) {
      int s = csr_src[rs + base + t];
      sbuf[t] = s;
      float e = el[s] + ern;
      e = e > 0.f ? e : 0.2f * e;
      float w = __expf(e);
      wbuf[t] = w;
      psum += w;
    }
    __syncthreads();
    int j = g;
    for (; j + 4 < cnt; j += 8) {
      int s0 = sbuf[j], s1 = sbuf[j + 4];
      float4 v0 = *(const float4*)(fd + (size_t)s0 * 128);
      float4 v1 = *(const float4*)(fd + (size_t)s1 * 128);
      float w0 = wbuf[j], w1 = wbuf[j + 4];
      acc.x += w0 * v0.x + w1 * v1.x;
      acc.y += w0 * v0.y + w1 * v1.y;
      acc.z += w0 * v0.z + w1 * v1.z;
      acc.w += w0 * v0.w + w1 * v1.w;
    }
    for (; j < cnt; j += 4) {
      int s = sbuf[j];
      float4 v = *(const float4*)(fd + (size_t)s * 128);
      float w = wbuf[j];
      acc.x += w * v.x; acc.y += w * v.y; acc.z += w * v.z; acc.w += w * v.w;
    }
    __syncthreads();
  }
  for (int off = 32; off; off >>= 1) psum += __shfl_down(psum, off);
  int wv = t >> 6, ln = t & 63;
  if (ln == 0) red[wv] = psum;
  accbuf[g][t & 31] = acc;
  __syncthreads();
  if (t < 32) {
    float4 a0 = accbuf[0][t], a1 = accbuf[1][t], a2 = accbuf[2][t], a3 = accbuf[3][t];
    float dn = red[0] + red[1];
    float inv = dn > 0.f ? 1.f / dn : 0.f;
    const float* bp = bias + t * 4;
    float4 r;
    r.x = (a0.x + a1.x + a2.x + a3.x) * inv + bp[0];
    r.y = (a0.y + a1.y + a2.y + a3.y) * inv + bp[1];
    r.z = (a0.z + a1.z + a2.z + a3.z) * inv + bp[2];
    r.w = (a0.w + a1.w + a2.w + a3.w) * inv + bp[3];
    *(float4*)&out[(size_t)n * 128 + t * 4] = r;
  }
}

// ---------------- mean-pool: 2-stage ----------------

__global__ void pool_partial_kernel(const float* __restrict__ h2, const int* __restrict__ gid,
                                    float* __restrict__ sums, int N) {
  int g = blockIdx.x / PSPLIT;
  int sp = blockIdx.x % PSPLIT;
  int tid = threadIdx.x;
  int lo0 = 0, hi0 = N;
  while (lo0 < hi0) { int m = (lo0 + hi0) >> 1; if (gid[m] < g) lo0 = m + 1; else hi0 = m; }
  int lo1 = lo0, hi1 = N;
  while (lo1 < hi1) { int m = (lo1 + hi1) >> 1; if (gid[m] < g + 1) lo1 = m + 1; else hi1 = m; }
  float a0 = 0.f, a1 = 0.f, a2 = 0.f, a3 = 0.f;
  int n = lo0 + sp;
  for (; n + 3 * PSPLIT < lo1; n += 4 * PSPLIT) {
    a0 += h2[(size_t)n * 128 + tid];
    a1 += h2[(size_t)(n + PSPLIT) * 128 + tid];
    a2 += h2[(size_t)(n + 2 * PSPLIT) * 128 + tid];
    a3 += h2[(size_t)(n + 3 * PSPLIT) * 128 + tid];
  }
  for (; n < lo1; n += PSPLIT) a0 += h2[(size_t)n * 128 + tid];
  float acc = (a0 + a1) + (a2 + a3);
  atomicAdd(&sums[g * 128 + tid], acc);
}

__global__ void pool_final_kernel(const float* __restrict__ sums, const int* __restrict__ gid,
                                  const float* __restrict__ linW, const float* __restrict__ linb,
                                  float* __restrict__ out, int N) {
  int g = blockIdx.x;
  int tid = threadIdx.x;
  int lo0 = 0, hi0 = N;
  while (lo0 < hi0) { int m = (lo0 + hi0) >> 1; if (gid[m] < g) lo0 = m + 1; else hi0 = m; }
  int lo1 = lo0, hi1 = N;
  while (lo1 < hi1) { int m = (lo1 + hi1) >> 1; if (gid[m] < g + 1) lo1 = m + 1; else hi1 = m; }
  int cnt = lo1 - lo0;
  float hg = sums[g * 128 + tid] / (float)(cnt > 0 ? cnt : 1);
  __shared__ float hgs[128];
  hgs[tid] = hg;
  __syncthreads();
  float o = linb[tid];
#pragma unroll 4
  for (int dd = 0; dd < 128; dd++) o += hgs[dd] * linW[dd * 128 + tid];
  out[g * 128 + tid] = fmaxf(o, 0.f);
}

// ---------------- launch ----------------

extern "C" void kernel_launch(void* const* d_in, const int* in_sizes, int n_in,
                              void* d_out, int out_size, void* d_ws, size_t ws_size,
                              hipStream_t stream) {
  const float* x    = (const float*)d_in[0];
  const int*   src  = (const int*)d_in[1];
  const int*   dst  = (const int*)d_in[2];
  const int*   gid  = (const int*)d_in[3];
  const float* W1   = (const float*)d_in[4];
  const float* al1  = (const float*)d_in[5];
  const float* ar1  = (const float*)d_in[6];
  const float* b1   = (const float*)d_in[7];
  const float* W2   = (const float*)d_in[8];
  const float* al2  = (const float*)d_in[9];
  const float* ar2  = (const float*)d_in[10];
  const float* b2   = (const float*)d_in[11];
  const float* linW = (const float*)d_in[12];
  const float* linb = (const float*)d_in[13];
  float* out = (float*)d_out;

  char* ws = (char*)d_ws;
  size_t off = 0;
  auto alloc = [&](size_t bytes) -> void* {
    void* p = ws + off;
    off += (bytes + 255) & ~(size_t)255;
    return p;
  };
  float* aggx    = (float*)alloc((size_t)NN * 384 * 4);  // reused as fpart (3x NN*128) after GEMM1
  float* h1      = (float*)alloc((size_t)NN * 384 * 4);
  float* f2      = (float*)alloc((size_t)NN * 128 * 4);
  float* h2      = (float*)alloc((size_t)NN * 128 * 4);
  float* el1     = (float*)alloc((size_t)NN * 3 * 4);
  float* er1     = (float*)alloc((size_t)NN * 3 * 4);
  float* el2     = (float*)alloc((size_t)NN * 4);
  float* er2     = (float*)alloc((size_t)NN * 4);
  float* wlr     = (float*)alloc((size_t)768 * 4);
  int*   rowptr  = (int*)alloc((size_t)(NN + 1) * 4);
  int*   csr_src = (int*)alloc((size_t)NE * 4);
  int*   bsum    = (int*)alloc((size_t)NSCANB * 4);
  int*   boff    = (int*)alloc((size_t)NSCANB * 4);
  // zero-initialized region (single memset): indeg, cursor, gsums
  int*   indeg   = (int*)alloc((size_t)NN * 4);
  int*   cursor  = (int*)alloc((size_t)NN * 4);
  float* gsums   = (float*)alloc((size_t)NG * 128 * 4);
  (void)ws_size;
  size_t zbytes = (char*)(gsums + NG * 128) - (char*)indeg;
  hipMemsetAsync(indeg, 0, zbytes, stream);

  // CSR build (hierarchical scan)
  hist_kernel<<<(NE + 255) / 256, 256, 0, stream>>>(dst, indeg, NE);
  scan1_kernel<<<NSCANB, 256, 0, stream>>>(indeg, rowptr, bsum, NN);
  scan2_kernel<<<1, 128, 0, stream>>>(bsum, boff, rowptr + NN, NSCANB);
  scan3_kernel<<<NSCANB, 256, 0, stream>>>(rowptr, boff, NN);
  scatter_kernel<<<(NE + 255) / 256, 256, 0, stream>>>(src, dst, rowptr, cursor, csr_src, NE);

  // Layer 1 (x-space): wlr -> el/er -> aggregate x -> per-head GEMM with bias+ELU
  prep_wlr_kernel<<<3, 256, 0, stream>>>(W1, al1, ar1, wlr);
  elr_kernel<<<(NN + 3) / 4, 256, 0, stream>>>(x, wlr, el1, er1, NN);
  aggregate_x_kernel<<<NN, 128, 0, stream>>>(x, el1, er1, rowptr, csr_src, aggx);
  gemm_8x8_kernel<3, false, true><<<157 * 3, 256, 0, stream>>>(
      aggx, 384, W1, 384, h1, 384, b1);

  // Layer 2: f2 = h1 @ W2 via K-split x3 (partials into fpart = reused aggx),
  // combined + el2/er2 in att_combine; aggregate(+b2) -> h2
  float* fpart = aggx;  // aggx dead after GEMM1; 3 * NN*128 floats fits exactly
  gemm_8x8_kernel<3, true, false><<<157 * 3, 256, 0, stream>>>(
      h1, 384, W2, 128, fpart, 128, nullptr);
  att_combine_kernel<<<(NN + 3) / 4, 256, 0, stream>>>(fpart, al2, ar2, f2, el2, er2, NN);
  aggregate1_kernel<<<NN, 128, 0, stream>>>(f2, el2, er2, b2, rowptr, csr_src, h2);

  // Mean-pool + linear head
  pool_partial_kernel<<<NG * PSPLIT, 128, 0, stream>>>(h2, gid, gsums, NN);
  pool_final_kernel<<<NG, 128, 0, stream>>>(gsums, gid, linW, linb, out, NN);
}